// Round 10
// baseline (654.714 us; speedup 1.0000x reference)
//
#include <hip/hip_runtime.h>
#include <hip/hip_cooperative_groups.h>
#include <math.h>

#define DEV __device__ __forceinline__

static constexpr int S_LEN  = 2048;
static constexpr int IN_DIM = 1024;
static constexpr int P_DIM  = 512;
static constexpr int NHEAD  = 8;
static constexpr int HD     = 64;
static constexpr int KN     = 128;

typedef __attribute__((ext_vector_type(8))) short bf16x8;
typedef __attribute__((ext_vector_type(4))) float f32x4;

DEV float gelu_exact(float x) {
    return 0.5f * x * (1.0f + erff(x * 0.70710678118654752440f));
}

// float -> bf16 (RNE), and the split residual helpers
DEV short bf_hi(float x) {
    unsigned u = __float_as_uint(x);
    unsigned r = (u + 0x7fffu + ((u >> 16) & 1u)) >> 16;
    return (short)r;
}
DEV float bf_f(short h) { return __uint_as_float(((unsigned)(unsigned short)h) << 16); }

// 256-thread block sum reduction. sm4 must be float[4] shared.
DEV float block_reduce_sum(float v, float* sm4) {
    #pragma unroll
    for (int off = 32; off; off >>= 1) v += __shfl_down(v, off, 64);
    int lane = threadIdx.x & 63, w = threadIdx.x >> 6;
    __syncthreads();
    if (lane == 0) sm4[w] = v;
    __syncthreads();
    return sm4[0] + sm4[1] + sm4[2] + sm4[3];
}

// wave-wide sum, deterministic butterfly
DEV float wave_sum(float v) {
    #pragma unroll
    for (int off = 32; off; off >>= 1) v += __shfl_xor(v, off, 64);
    return v;
}

// ---------------- K_prep: fused cent + weight transposes + seq split --------
DEV void wt_body(const float* __restrict__ W, short* __restrict__ WTh,
                 short* __restrict__ WTl, int K, int N, int bk, int bn,
                 float (*tile)[65]) {
    int t = threadIdx.x;
    int c = t & 63, r4 = t >> 6;
    #pragma unroll
    for (int i = 0; i < 16; i++) {
        int row = r4 + i * 4;
        tile[row][c] = W[(long)(bk * 64 + row) * N + bn * 64 + c];
    }
    __syncthreads();
    #pragma unroll
    for (int i = 0; i < 16; i++) {
        int n = r4 + i * 4;
        float v = tile[c][n];
        short h = bf_hi(v);
        long o = (long)(bn * 64 + n) * K + bk * 64 + c;
        WTh[o] = h;
        WTl[o] = bf_hi(v - bf_f(h));
    }
}

DEV void t32_body(const float* __restrict__ W, float* __restrict__ WT,
                  int K, int N, int bk, int bn, float (*tile)[65]) {
    int t = threadIdx.x;
    int c = t & 63, r4 = t >> 6;
    #pragma unroll
    for (int i = 0; i < 16; i++) {
        int row = r4 + i * 4;
        tile[row][c] = W[(long)(bk * 64 + row) * N + bn * 64 + c];
    }
    __syncthreads();
    #pragma unroll
    for (int i = 0; i < 16; i++) {
        int n = r4 + i * 4;
        WT[(long)(bn * 64 + n) * K + bk * 64 + c] = tile[c][n];
    }
}

__global__ __launch_bounds__(256) void k_prep(const float* __restrict__ penta,
                                              short* __restrict__ ch, short* __restrict__ cl,
                                              const float* __restrict__ projW,
                                              short* __restrict__ pjh, short* __restrict__ pjl,
                                              const float* __restrict__ qkvW,
                                              short* __restrict__ qkh, short* __restrict__ qkl,
                                              const float* __restrict__ seq,
                                              short* __restrict__ sh, short* __restrict__ sl,
                                              unsigned long long* __restrict__ rowkey,
                                              float* __restrict__ pooledZ,
                                              const float* __restrict__ outW, float* __restrict__ outWT,
                                              const float* __restrict__ w1_0,
                                              const float* __restrict__ w1_1,
                                              const float* __restrict__ w1_2, float* __restrict__ w1T,
                                              const float* __restrict__ w2_0,
                                              const float* __restrict__ w2_1,
                                              const float* __restrict__ w2_2, float* __restrict__ w2T) {
    __shared__ float tile[64][65];
    __shared__ float sm4[4];
    int blk = blockIdx.x, t = threadIdx.x;
    if (blk < 1024) {
        int p = blk;
        if (t < 4) rowkey[p * 4 + t] = 0ull;
        if (p < 4) pooledZ[p * 256 + t] = 0.f;
        float c0 = 0.f, c1 = 0.f;
        #pragma unroll
        for (int v = 0; v < 5; v++) {
            const float* row = penta + ((long)p * 5 + v) * P_DIM;
            c0 += row[t];
            c1 += row[t + 256];
        }
        c0 /= 5.0f; c1 /= 5.0f;
        float tot = block_reduce_sum(c0 * c0 + c1 * c1, sm4);
        float n = fmaxf(sqrtf(tot), 1e-12f);
        float v0 = c0 / n, v1 = c1 / n;
        short h0 = bf_hi(v0), h1 = bf_hi(v1);
        ch[p * P_DIM + t]       = h0;
        ch[p * P_DIM + t + 256] = h1;
        cl[p * P_DIM + t]       = bf_hi(v0 - bf_f(h0));
        cl[p * P_DIM + t + 256] = bf_hi(v1 - bf_f(h1));
    } else if (blk < 1152) {
        int id = blk - 1024;                 // 16 x 8
        wt_body(projW, pjh, pjl, IN_DIM, P_DIM, id & 15, id >> 4, tile);
    } else if (blk < 1344) {
        int id = blk - 1152;                 // 8 x 24
        wt_body(qkvW, qkh, qkl, P_DIM, 3 * P_DIM, id & 7, id >> 3, tile);
    } else if (blk < 2368) {
        long base = ((long)(blk - 1344) * 256 + t) * 16;
        #pragma unroll
        for (int u = 0; u < 4; u++) {
            float4 v = *(const float4*)(seq + base + u * 4);
            short h0 = bf_hi(v.x), h1 = bf_hi(v.y), h2 = bf_hi(v.z), h3 = bf_hi(v.w);
            *(short4*)(sh + base + u * 4) = make_short4(h0, h1, h2, h3);
            *(short4*)(sl + base + u * 4) =
                make_short4(bf_hi(v.x - bf_f(h0)), bf_hi(v.y - bf_f(h1)),
                            bf_hi(v.z - bf_f(h2)), bf_hi(v.w - bf_f(h3)));
        }
    } else if (blk < 2432) {
        int id = blk - 2368;                 // outW 512x512: 8x8
        t32_body(outW, outWT, 512, 512, id & 7, id >> 3, tile);
    } else if (blk < 2464) {
        int id = blk - 2432;                 // w1_0 512x256 -> rows [0,256)
        t32_body(w1_0, w1T, 512, 256, id & 7, id >> 3, tile);
    } else if (blk < 2528) {
        int id = blk - 2464;                 // w1_1 512x512 -> rows [256,768)
        t32_body(w1_1, w1T + 256 * 512, 512, 512, id & 7, id >> 3, tile);
    } else if (blk < 2656) {
        int id = blk - 2528;                 // w1_2 512x1024 -> rows [768,1792)
        t32_body(w1_2, w1T + 768 * 512, 512, 1024, id & 7, id >> 3, tile);
    } else if (blk < 2664) {
        int id = blk - 2656;                 // w2_0 256x128
        t32_body(w2_0, w2T, 256, 128, id & 3, id >> 2, tile);
    } else if (blk < 2696) {
        int id = blk - 2664;                 // w2_1 512x256
        t32_body(w2_1, w2T + 32768, 512, 256, id & 7, id >> 3, tile);
    } else {
        int id = blk - 2696;                 // w2_2 1024x512
        t32_body(w2_2, w2T + 163840, 1024, 512, id & 15, id >> 4, tile);
    }
}

// ---------------- MFMA split-bf16 GEMM: C = A@W + bias ----------------------
// BM x 128 block tile, BK=64, 4 waves in 2x2, wave tile (BM/2) x 64.
template <int BM, int K, int N, int EPI>
__global__ __launch_bounds__(256) void k_mm(const short* __restrict__ Ash,
                                            const short* __restrict__ Asl,
                                            const short* __restrict__ BTh,
                                            const short* __restrict__ BTl,
                                            const float* __restrict__ bias,
                                            float* __restrict__ C,
                                            unsigned long long* __restrict__ rowkey) {
    constexpr int TI  = BM / 32;      // i-tiles (of 16 rows) per wave
    constexpr int CA  = BM / 8;       // 1KB staging chunks per A array
    constexpr int NCH = 2 * CA + 32;  // + 16 chunks each for Bh, Bl
    __shared__ __align__(128) short AhS[BM * 64], AlS[BM * 64];
    __shared__ __align__(128) short BhS[128 * 64], BlS[128 * 64];
    int t = threadIdx.x;
    int lane = t & 63, wave = t >> 6;
    int wr = (wave >> 1) * (BM / 2), wc = (wave & 1) * 64;
    int m = lane & 15, quad = lane >> 4;
    int rb = blockIdx.x * BM, cb = blockIdx.y * 128;
    int r8 = lane >> 3, p8 = lane & 7;
    int sl = p8 ^ r8;                 // pre-swizzled 16B source slot

    f32x4 acc[TI][4];
    #pragma unroll
    for (int i = 0; i < TI; i++)
        #pragma unroll
        for (int j = 0; j < 4; j++) acc[i][j] = (f32x4){0.f, 0.f, 0.f, 0.f};

    for (int k0 = 0; k0 < K; k0 += 64) {
        __syncthreads();
        for (int c = wave; c < NCH; c += 4) {
            const short* src; short* dst;
            if (c < CA) {
                src = Ash + (long)(rb + c * 8 + r8) * K + k0 + sl * 8;
                dst = AhS + c * 512;
            } else if (c < 2 * CA) {
                int cc = c - CA;
                src = Asl + (long)(rb + cc * 8 + r8) * K + k0 + sl * 8;
                dst = AlS + cc * 512;
            } else if (c < 2 * CA + 16) {
                int cc = c - 2 * CA;
                src = BTh + (long)(cb + cc * 8 + r8) * K + k0 + sl * 8;
                dst = BhS + cc * 512;
            } else {
                int cc = c - 2 * CA - 16;
                src = BTl + (long)(cb + cc * 8 + r8) * K + k0 + sl * 8;
                dst = BlS + cc * 512;
            }
            __builtin_amdgcn_global_load_lds(
                (const __attribute__((address_space(1))) unsigned int*)src,
                (__attribute__((address_space(3))) unsigned int*)dst, 16, 0, 0);
        }
        __syncthreads();

        #pragma unroll
        for (int ks = 0; ks < 2; ks++) {
            int so = ((ks * 4 + quad) ^ (m & 7)) * 8;
            bf16x8 ah[TI], al[TI], bh[4], bl[4];
            #pragma unroll
            for (int i = 0; i < TI; i++) {
                int off = (wr + i * 16 + m) * 64 + so;
                ah[i] = *(const bf16x8*)(AhS + off);
                al[i] = *(const bf16x8*)(AlS + off);
            }
            #pragma unroll
            for (int j = 0; j < 4; j++) {
                int off = (wc + j * 16 + m) * 64 + so;
                bh[j] = *(const bf16x8*)(BhS + off);
                bl[j] = *(const bf16x8*)(BlS + off);
            }
            #pragma unroll
            for (int i = 0; i < TI; i++)
                #pragma unroll
                for (int j = 0; j < 4; j++) {
                    acc[i][j] = __builtin_amdgcn_mfma_f32_16x16x32_bf16(ah[i], bh[j], acc[i][j], 0, 0, 0);
                    acc[i][j] = __builtin_amdgcn_mfma_f32_16x16x32_bf16(ah[i], bl[j], acc[i][j], 0, 0, 0);
                    acc[i][j] = __builtin_amdgcn_mfma_f32_16x16x32_bf16(al[i], bh[j], acc[i][j], 0, 0, 0);
                }
        }
    }

    if (EPI == 0) {
        #pragma unroll
        for (int i = 0; i < TI; i++) {
            int gr0 = rb + wr + i * 16 + quad * 4;
            #pragma unroll
            for (int j = 0; j < 4; j++) {
                int gc = cb + wc + j * 16 + m;
                float bv = bias[gc];
                #pragma unroll
                for (int r = 0; r < 4; r++)
                    C[(long)(gr0 + r) * N + gc] = acc[i][j][r] + bv;
            }
        }
    } else {
        #pragma unroll
        for (int i = 0; i < TI; i++) {
            #pragma unroll
            for (int r = 0; r < 4; r++) {
                int gr = rb + wr + i * 16 + quad * 4 + r;
                float bv = acc[i][0][r];
                int bp = cb + wc + m;
                #pragma unroll
                for (int j = 1; j < 4; j++) {
                    float v = acc[i][j][r];
                    int p = cb + wc + j * 16 + m;
                    if (v > bv) { bv = v; bp = p; }
                }
                #pragma unroll
                for (int off = 1; off < 16; off <<= 1) {
                    float ov = __shfl_xor(bv, off, 64);
                    int op = __shfl_xor(bp, off, 64);
                    if (ov > bv || (ov == bv && op < bp)) { bv = ov; bp = op; }
                }
                if (m == 0) {
                    unsigned u = __float_as_uint(bv);
                    u = (u & 0x80000000u) ? ~u : (u | 0x80000000u);
                    unsigned long long key =
                        ((unsigned long long)u << 32) | (unsigned)(0xFFFFFFFFu - (unsigned)bp);
                    atomicMax(&rowkey[gr], key);
                }
            }
        }
    }
}

// ---------------- K4: FUSED anchor + qkv GEMM (BM=64, 1280 blocks) ----------
__global__ __launch_bounds__(256) void k_mmz(const short* __restrict__ Ash,
                                             const short* __restrict__ Asl,
                                             const short* __restrict__ Ch,
                                             const short* __restrict__ Cl,
                                             const short* __restrict__ Qh,
                                             const short* __restrict__ Ql,
                                             const float* __restrict__ bias,
                                             float* __restrict__ C,
                                             unsigned long long* __restrict__ rowkey) {
    constexpr int BM = 64, K = 512;
    constexpr int TI  = BM / 32;
    constexpr int CA  = BM / 8;
    constexpr int NCH = 2 * CA + 32;
    __shared__ __align__(128) short AhS[BM * 64], AlS[BM * 64];
    __shared__ __align__(128) short BhS[128 * 64], BlS[128 * 64];
    int t = threadIdx.x;
    int lane = t & 63, wave = t >> 6;
    int wr = (wave >> 1) * (BM / 2), wc = (wave & 1) * 64;
    int m = lane & 15, quad = lane >> 4;
    bool anchor = blockIdx.y < 8;
    const short* BTh = anchor ? Ch : Qh;
    const short* BTl = anchor ? Cl : Ql;
    int rb = blockIdx.x * BM;
    int cb = (anchor ? blockIdx.y : (blockIdx.y - 8)) * 128;
    int r8 = lane >> 3, p8 = lane & 7;
    int sl = p8 ^ r8;

    f32x4 acc[TI][4];
    #pragma unroll
    for (int i = 0; i < TI; i++)
        #pragma unroll
        for (int j = 0; j < 4; j++) acc[i][j] = (f32x4){0.f, 0.f, 0.f, 0.f};

    for (int k0 = 0; k0 < K; k0 += 64) {
        __syncthreads();
        for (int c = wave; c < NCH; c += 4) {
            const short* src; short* dst;
            if (c < CA) {
                src = Ash + (long)(rb + c * 8 + r8) * K + k0 + sl * 8;
                dst = AhS + c * 512;
            } else if (c < 2 * CA) {
                int cc = c - CA;
                src = Asl + (long)(rb + cc * 8 + r8) * K + k0 + sl * 8;
                dst = AlS + cc * 512;
            } else if (c < 2 * CA + 16) {
                int cc = c - 2 * CA;
                src = BTh + (long)(cb + cc * 8 + r8) * K + k0 + sl * 8;
                dst = BhS + cc * 512;
            } else {
                int cc = c - 2 * CA - 16;
                src = BTl + (long)(cb + cc * 8 + r8) * K + k0 + sl * 8;
                dst = BlS + cc * 512;
            }
            __builtin_amdgcn_global_load_lds(
                (const __attribute__((address_space(1))) unsigned int*)src,
                (__attribute__((address_space(3))) unsigned int*)dst, 16, 0, 0);
        }
        __syncthreads();

        #pragma unroll
        for (int ks = 0; ks < 2; ks++) {
            int so = ((ks * 4 + quad) ^ (m & 7)) * 8;
            bf16x8 ah[TI], al[TI], bh[4], bl[4];
            #pragma unroll
            for (int i = 0; i < TI; i++) {
                int off = (wr + i * 16 + m) * 64 + so;
                ah[i] = *(const bf16x8*)(AhS + off);
                al[i] = *(const bf16x8*)(AlS + off);
            }
            #pragma unroll
            for (int j = 0; j < 4; j++) {
                int off = (wc + j * 16 + m) * 64 + so;
                bh[j] = *(const bf16x8*)(BhS + off);
                bl[j] = *(const bf16x8*)(BlS + off);
            }
            #pragma unroll
            for (int i = 0; i < TI; i++)
                #pragma unroll
                for (int j = 0; j < 4; j++) {
                    acc[i][j] = __builtin_amdgcn_mfma_f32_16x16x32_bf16(ah[i], bh[j], acc[i][j], 0, 0, 0);
                    acc[i][j] = __builtin_amdgcn_mfma_f32_16x16x32_bf16(ah[i], bl[j], acc[i][j], 0, 0, 0);
                    acc[i][j] = __builtin_amdgcn_mfma_f32_16x16x32_bf16(al[i], bh[j], acc[i][j], 0, 0, 0);
                }
        }
    }

    if (!anchor) {
        #pragma unroll
        for (int i = 0; i < TI; i++) {
            int gr0 = rb + wr + i * 16 + quad * 4;
            #pragma unroll
            for (int j = 0; j < 4; j++) {
                int gc = cb + wc + j * 16 + m;
                float bv = bias[gc];
                #pragma unroll
                for (int r = 0; r < 4; r++)
                    C[(long)(gr0 + r) * 1536 + gc] = acc[i][j][r] + bv;
            }
        }
    } else {
        #pragma unroll
        for (int i = 0; i < TI; i++) {
            #pragma unroll
            for (int r = 0; r < 4; r++) {
                int gr = rb + wr + i * 16 + quad * 4 + r;
                float bv = acc[i][0][r];
                int bp = cb + wc + m;
                #pragma unroll
                for (int j = 1; j < 4; j++) {
                    float v = acc[i][j][r];
                    int p = cb + wc + j * 16 + m;   // ascending; > keeps lowest p
                    if (v > bv) { bv = v; bp = p; }
                }
                #pragma unroll
                for (int off = 1; off < 16; off <<= 1) {
                    float ov = __shfl_xor(bv, off, 64);
                    int op = __shfl_xor(bp, off, 64);
                    if (ov > bv || (ov == bv && op < bp)) { bv = ov; bp = op; }
                }
                if (m == 0) {
                    unsigned u = __float_as_uint(bv);
                    u = (u & 0x80000000u) ? ~u : (u | 0x80000000u);
                    unsigned long long key =
                        ((unsigned long long)u << 32) | (unsigned)(0xFFFFFFFFu - (unsigned)bp);
                    atomicMax(&rowkey[gr], key);
                }
            }
        }
    }
}

// ---------------- K3: LayerNorm -> gelu -> L2 norm -> emit SPLIT bf16 -------
__global__ __launch_bounds__(256) void k_ln_gelu_norm(const float* __restrict__ Zin,
                                                      const float* __restrict__ g,
                                                      const float* __restrict__ b,
                                                      short* __restrict__ z_h,
                                                      short* __restrict__ z_l) {
    long row = blockIdx.x;
    int t = threadIdx.x;
    __shared__ float sm4[4];
    float x0 = Zin[row * P_DIM + t], x1 = Zin[row * P_DIM + t + 256];
    float mu = block_reduce_sum(x0 + x1, sm4) * (1.0f / P_DIM);
    float d0 = x0 - mu, d1 = x1 - mu;
    float var = block_reduce_sum(d0 * d0 + d1 * d1, sm4) * (1.0f / P_DIM);
    float rs = 1.0f / sqrtf(var + 1e-5f);
    float y0 = gelu_exact(d0 * rs * g[t] + b[t]);
    float y1 = gelu_exact(d1 * rs * g[t + 256] + b[t + 256]);
    float nn = block_reduce_sum(y0 * y0 + y1 * y1, sm4);
    float n = fmaxf(sqrtf(nn), 1e-12f);
    float v0 = y0 / n, v1 = y1 / n;
    short h0 = bf_hi(v0), h1 = bf_hi(v1);
    z_h[row * P_DIM + t]       = h0;
    z_h[row * P_DIM + t + 256] = h1;
    z_l[row * P_DIM + t]       = bf_hi(v0 - bf_f(h0));
    z_l[row * P_DIM + t + 256] = bf_hi(v1 - bf_f(h1));
}

// ---------------- K5: O(N^2) rank sort ---------------------------------------
__global__ __launch_bounds__(256) void k_rank(const unsigned long long* __restrict__ rowkey,
                                              const float* __restrict__ spos,
                                              int* __restrict__ order,
                                              float* __restrict__ pos_srt) {
    int b = blockIdx.y, t = threadIdx.x;
    __shared__ unsigned long long key[2048];
    for (int u = 0; u < 8; u++) {
        int i = t + u * 256;
        unsigned p = 0xFFFFFFFFu - (unsigned)(rowkey[b * 2048 + i] & 0xFFFFFFFFull);
        key[i] = (((unsigned long long)__float_as_uint(spos[p])) << 32) | (unsigned)i;
    }
    __syncthreads();
    int i = blockIdx.x * 256 + t;
    unsigned long long ki = key[i];
    int rank = 0;
    #pragma unroll 8
    for (int j = 0; j < 2048; j++) rank += (key[j] < ki) ? 1 : 0;
    order[b * 2048 + rank]   = i;
    pos_srt[b * 2048 + rank] = __uint_as_float((unsigned)(ki >> 32));
}

// ---------------- K6: FUSED routes (top-128 bitmap) + K/V prep ---------------
__global__ __launch_bounds__(256) void k_routeskv(const float* __restrict__ pos_srt,
                                                  const int* __restrict__ order,
                                                  unsigned long long* __restrict__ bmG,
                                                  uint2* __restrict__ bounds,
                                                  const float* __restrict__ qkv,
                                                  short* __restrict__ Ks_h,
                                                  short* __restrict__ Ks_l,
                                                  short* __restrict__ Vt_h) {
    __shared__ __align__(16) char smem[12288];
    int blk0 = blockIdx.x, t = threadIdx.x;
    if (blk0 < 1024) {
        float* ps = (float*)smem;                       // 2048 floats
        unsigned short* tk = (unsigned short*)(smem + 8192); // 2048 u16
        int blk = blk0;
        int b = blk >> 9;
        int lane = t & 63, wave = t >> 6;
        int r = (blk & 511) * 4 + wave;
        for (int u = 0; u < 8; u++) {
            int i = t + u * 256;
            ps[i] = pos_srt[b * 2048 + i];
            tk[i] = (unsigned short)order[b * 2048 + i];
        }
        __syncthreads();

        float pi = ps[r];
        float T = 3e38f;
        #pragma unroll
        for (int a2 = 0; a2 < 2; a2++) {
            int a = lane + a2 * 64;
            int jl = r - a, jr = r + 127 - a;
            if (jl >= 0 && jr <= 2047) {
                float dl = (a > 0)   ? (pi - ps[jl]) : 0.f;
                float dr = (a < 127) ? (ps[jr] - pi) : 0.f;
                T = fminf(T, fmaxf(dl, dr));
            }
        }
        #pragma unroll
        for (int off = 1; off < 64; off <<= 1) T = fminf(T, __shfl_xor(T, off, 64));

        int lo = 0, hi = r;
        while (lo < hi) { int mid = (lo + hi) >> 1; if (pi - ps[mid] <= T) hi = mid; else lo = mid + 1; }
        int mn = lo;
        lo = r; hi = 2047;
        while (lo < hi) { int mid = (lo + hi + 1) >> 1; if (ps[mid] - pi <= T) lo = mid; else hi = mid - 1; }
        int mx = lo;
        int Ls, Rs;
        if (T > 0.f) {
            lo = 0; hi = r;
            while (lo < hi) { int mid = (lo + hi) >> 1; if (pi - ps[mid] < T) hi = mid; else lo = mid + 1; }
            Ls = lo;
            lo = r; hi = 2047;
            while (lo < hi) { int mid = (lo + hi + 1) >> 1; if (ps[mid] - pi < T) lo = mid; else hi = mid - 1; }
            Rs = lo;
        } else { Ls = r + 1; Rs = r - 1; }

        int cnt_strict = (Rs >= Ls) ? (Rs - Ls + 1) : 0;
        int need = 128 - cnt_strict;
        int l0a, l0b, r0a, r0b;
        if (cnt_strict > 0) { l0a = mn; l0b = Ls - 1; r0a = Rs + 1; r0b = mx; }
        else                { l0a = mn; l0b = mx;     r0a = 1;      r0b = 0; }
        int nL = (l0b >= l0a) ? (l0b - l0a + 1) : 0;
        int nR = (r0b >= r0a) ? (r0b - r0a + 1) : 0;
        int tiecount = nL + nR;

        int X = 65535;
        if (need < tiecount) {
            int lo2 = 0, hi2 = 2047;
            while (lo2 < hi2) {
                int mid = (lo2 + hi2) >> 1;
                int cnt = 0;
                for (int e = lane; e < tiecount; e += 64) {
                    int j = (e < nL) ? (l0a + e) : (r0a + e - nL);
                    cnt += (tk[j] <= mid) ? 1 : 0;
                }
                #pragma unroll
                for (int off = 1; off < 64; off <<= 1) cnt += __shfl_xor(cnt, off, 64);
                if (cnt >= need) hi2 = mid; else lo2 = mid + 1;
            }
            X = lo2;
        }

        int qlo_loc = 1 << 30, qhi_loc = -1;
        if (lane < 32) {
            unsigned long long bits = 0;
            int j0 = lane << 6, j1 = j0 + 63;
            if (cnt_strict > 0) {
                int a0 = max(Ls, j0), a1 = min(Rs, j1);
                if (a0 <= a1) {
                    int s = a0 - j0, e = a1 - j0;
                    unsigned long long msk = (e - s == 63) ? ~0ull
                                           : (((1ull << (e - s + 1)) - 1) << s);
                    bits |= msk;
                }
            }
            int a0 = max(l0a, j0), a1 = min(l0b, j1);
            for (int j = a0; j <= a1; j++) if (tk[j] <= X) bits |= 1ull << (j - j0);
            a0 = max(r0a, j0); a1 = min(r0b, j1);
            for (int j = a0; j <= a1; j++) if (tk[j] <= X) bits |= 1ull << (j - j0);
            if (bits) {
                qlo_loc = j0 + __builtin_ctzll(bits);
                qhi_loc = j0 + 63 - __builtin_clzll(bits);
            }
            bmG[((long)(b * 2048 + r)) * 32 + lane] = bits;
        }
        #pragma unroll
        for (int off = 1; off < 64; off <<= 1) {
            qlo_loc = min(qlo_loc, __shfl_xor(qlo_loc, off, 64));
            qhi_loc = max(qhi_loc, __shfl_xor(qhi_loc, off, 64));
        }
        if (lane == 0)
            bounds[b * 2048 + r] = make_uint2((unsigned)qlo_loc, (unsigned)qhi_loc);
    } else if (blk0 < 1536) {
        int blk = blk0 - 1024;                 // K prep
        int b = blk >> 8, bx = blk & 255;
        int lr = t >> 5;
        int seg = t & 31;
        int rank = bx * 8 + lr;
        int tok = order[b * 2048 + rank];
        const float4* src = (const float4*)qkv + (long)(b * 2048 + tok) * 384 + 128 + seg * 4;
        long dsto = (long)(b * 2048 + rank) * 512 + seg * 16;
        #pragma unroll
        for (int u = 0; u < 4; u++) {
            float4 v = src[u];
            short h0 = bf_hi(v.x), h1 = bf_hi(v.y), h2 = bf_hi(v.z), h3 = bf_hi(v.w);
            *(short4*)(Ks_h + dsto + u * 4) = make_short4(h0, h1, h2, h3);
            *(short4*)(Ks_l + dsto + u * 4) =
                make_short4(bf_hi(v.x - bf_f(h0)), bf_hi(v.y - bf_f(h1)),
                            bf_hi(v.z - bf_f(h2)), bf_hi(v.w - bf_f(h3)));
        }
    } else {
        short (*tile)[72] = (short(*)[72])smem;   // 64 x 72 shorts = 9216 B
        int id = blk0 - 1536;                  // V prep
        int rt = id & 31, dt = (id >> 5) & 7, b = id >> 8;
        int lr = t >> 2;
        int q4 = t & 3;
        int tok = order[b * 2048 + rt * 64 + lr];
        const float4* src = (const float4*)qkv + (long)(b * 2048 + tok) * 384 + 256 + dt * 16;
        #pragma unroll
        for (int u = 0; u < 4; u++) {
            float4 v = src[q4 + u * 4];
            int d0 = (q4 + u * 4) * 4;
            tile[d0 + 0][lr] = bf_hi(v.x);
            tile[d0 + 1][lr] = bf_hi(v.y);
            tile[d0 + 2][lr] = bf_hi(v.z);
            tile[d0 + 3][lr] = bf_hi(v.w);
        }
        __syncthreads();
        int d = t >> 2, c4 = t & 3;
        long o = ((long)(b * 512 + dt * 64 + d)) * 2048 + rt * 64 + c4 * 16;
        #pragma unroll
        for (int j = 0; j < 4; j++)
            *(short4*)(Vt_h + o + j * 4) = make_short4(tile[d][c4 * 16 + j * 4 + 0],
                                                       tile[d][c4 * 16 + j * 4 + 1],
                                                       tile[d][c4 * 16 + j * 4 + 2],
                                                       tile[d][c4 * 16 + j * 4 + 3]);
    }
}

// ---------------- K7: MFMA flash attention (direct-global K/V) --------------
__global__ __launch_bounds__(256) void k_attn(const float* __restrict__ qkv,
                                              const int* __restrict__ order,
                                              const unsigned long long* __restrict__ bmG,
                                              const uint2* __restrict__ bounds,
                                              const short* __restrict__ Ks_h,
                                              const short* __restrict__ Ks_l,
                                              const short* __restrict__ Vt_h,
                                              float* __restrict__ pooledZ) {
    __shared__ __align__(16) char smem[17280];
    short* Pt = (short*)smem;                               // 4 waves x 1280 shorts
    unsigned short* cm = (unsigned short*)(smem + 10240);   // 128 x 16
    float* Opart = (float*)smem;                            // alias: [2][16][128]
    float2* ml = (float2*)(smem + 16384);                   // [2][2][16]
    int* sh_tok = (int*)(smem + 16896);                     // 16
    int* sh_lohi = (int*)(smem + 16960);                    // 2
    float2* sc = (float2*)(smem + 16968);                   // [2][16] w0*inv, w1*inv

    int gb = blockIdx.x;
    int b  = gb >> 9;
    int qg = (gb >> 2) & 127;
    int hp = gb & 3;
    int h0 = hp * 2;
    int r0 = qg * 16;
    int t = threadIdx.x;
    int lane = t & 63, wave = t >> 6;
    int rh = wave & 1, hs = wave >> 1;
    int key = lane & 15, quad = lane >> 4;

    const float4* qkvF4 = (const float4*)qkv;

    if (t < 16) sh_tok[t] = order[b * 2048 + r0 + t];
    if (t == 0) { sh_lohi[0] = 1 << 30; sh_lohi[1] = 0; }
    #pragma unroll
    for (int u = 0; u < 8; u++) {
        int e = t + u * 256;
        int c = e >> 4, q = e & 15;
        cm[c * 16 + q] = (unsigned short)(
            (bmG[((long)(b * 2048 + r0 + q)) * 32 + (c >> 2)] >> ((c & 3) * 16)) & 0xFFFF);
    }
    __syncthreads();
    if (t < 16) {
        uint2 bd = bounds[b * 2048 + r0 + t];
        atomicMin(&sh_lohi[0], (int)bd.x);
        atomicMax(&sh_lohi[1], (int)bd.y);
    }

    bf16x8 qh[2], ql[2];
    {
        long tq = (long)(b * 2048 + sh_tok[key]) * 384;
        #pragma unroll
        for (int ks = 0; ks < 2; ks++) {
            float4 v0 = qkvF4[tq + (h0 + hs) * 16 + ks * 8 + quad * 2];
            float4 v1 = qkvF4[tq + (h0 + hs) * 16 + ks * 8 + quad * 2 + 1];
            float vv[8] = {v0.x, v0.y, v0.z, v0.w, v1.x, v1.y, v1.z, v1.w};
            #pragma unroll
            for (int j = 0; j < 8; j++) {
                short hb = bf_hi(vv[j]);
                qh[ks][j] = hb;
                ql[ks][j] = bf_hi(vv[j] - bf_f(hb));
            }
        }
    }
    __syncthreads();
    int lo = sh_lohi[0] & ~63, hi = sh_lohi[1] + 1;

    float mrow[4], lrow[4];
    f32x4 Ont[4];
    #pragma unroll
    for (int r = 0; r < 4; r++) { mrow[r] = -1e30f; lrow[r] = 0.f; }
    #pragma unroll
    for (int nt = 0; nt < 4; nt++) Ont[nt] = (f32x4){0.f, 0.f, 0.f, 0.f};

    short* PtH = Pt + wave * 1280;
    short* PtL = PtH + 640;

    int hd = h0 + hs;
    long kbase = ((long)b * 2048) * 512 + hd * 64 + quad * 8;
    long vbase = ((long)(b * 512 + hd * 64 + key)) * 2048;

    // NOTE: no __syncthreads() in this loop — waves run fully independently,
    // so s_setprio around the MFMA clusters pays (T5 / m191 regime).
    for (int c0 = lo; c0 < hi; c0 += 64) {
        int cb = c0 + rh * 32;
        if (cb >= hi) continue;
        int ch0 = cb >> 4;
        unsigned long long m0 = *(const unsigned long long*)(cm + ch0 * 16 + quad * 4);
        unsigned long long m1 = (ch0 + 1 < 128)
            ? *(const unsigned long long*)(cm + (ch0 + 1) * 16 + quad * 4) : 0ull;
        if (!__any((m0 | m1) != 0ull)) continue;

        long kr0 = kbase + (long)(cb + key) * 512;
        long kr1 = kbase + (long)(cb + 16 + key) * 512;

        f32x4 S0 = (f32x4){0.f,0.f,0.f,0.f}, S1 = (f32x4){0.f,0.f,0.f,0.f};
        __builtin_amdgcn_s_setprio(1);
        #pragma unroll
        for (int ks = 0; ks < 2; ks++) {
            bf16x8 b0h = *(const bf16x8*)(Ks_h + kr0 + ks * 32);
            bf16x8 b0l = *(const bf16x8*)(Ks_l + kr0 + ks * 32);
            bf16x8 b1h = *(const bf16x8*)(Ks_h + kr1 + ks * 32);
            bf16x8 b1l = *(const bf16x8*)(Ks_l + kr1 + ks * 32);
            S0 = __builtin_amdgcn_mfma_f32_16x16x32_bf16(qh[ks], b0h, S0, 0, 0, 0);
            S0 = __builtin_amdgcn_mfma_f32_16x16x32_bf16(qh[ks], b0l, S0, 0, 0, 0);
            S0 = __builtin_amdgcn_mfma_f32_16x16x32_bf16(ql[ks], b0h, S0, 0, 0, 0);
            S1 = __builtin_amdgcn_mfma_f32_16x16x32_bf16(qh[ks], b1h, S1, 0, 0, 0);
            S1 = __builtin_amdgcn_mfma_f32_16x16x32_bf16(qh[ks], b1l, S1, 0, 0, 0);
            S1 = __builtin_amdgcn_mfma_f32_16x16x32_bf16(ql[ks], b1h, S1, 0, 0, 0);
        }
        __builtin_amdgcn_s_setprio(0);
        float s0[4], s1[4], p0[4], p1[4];
        unsigned bit0[4], bit1[4];
        #pragma unroll
        for (int r = 0; r < 4; r++) {
            bit0[r] = (unsigned)((m0 >> (r * 16 + key)) & 1);
            bit1[r] = (unsigned)((m1 >> (r * 16 + key)) & 1);
            s0[r] = bit0[r] ? S0[r] * 0.125f : -1e30f;
            s1[r] = bit1[r] ? S1[r] * 0.125f : -1e30f;
        }
        #pragma unroll
        for (int r = 0; r < 4; r++) {
            float cmax = fmaxf(s0[r], s1[r]);
            cmax = fmaxf(cmax, __shfl_xor(cmax, 1, 64));
            cmax = fmaxf(cmax, __shfl_xor(cmax, 2, 64));
            cmax = fmaxf(cmax, __shfl_xor(cmax, 4, 64));
            cmax = fmaxf(cmax, __shfl_xor(cmax, 8, 64));
            float mn = fmaxf(mrow[r], cmax);
            float alpha = __expf(mrow[r] - mn);
            mrow[r] = mn;
            p0[r] = bit0[r] ? __expf(s0[r] - mn) : 0.f;
            p1[r] = bit1[r] ? __expf(s1[r] - mn) : 0.f;
            float rs = p0[r] + p1[r];
            rs += __shfl_xor(rs, 1, 64);
            rs += __shfl_xor(rs, 2, 64);
            rs += __shfl_xor(rs, 4, 64);
            rs += __shfl_xor(rs, 8, 64);
            lrow[r] = lrow[r] * alpha + rs;
            #pragma unroll
            for (int nt = 0; nt < 4; nt++) Ont[nt][r] *= alpha;
        }
        #pragma unroll
        for (int r = 0; r < 4; r++) {
            short ha = bf_hi(p0[r]);
            PtH[(quad * 4 + r) * 40 + key] = ha;
            PtL[(quad * 4 + r) * 40 + key] = bf_hi(p0[r] - bf_f(ha));
            short hb = bf_hi(p1[r]);
            PtH[(quad * 4 + r) * 40 + 16 + key] = hb;
            PtL[(quad * 4 + r) * 40 + 16 + key] = bf_hi(p1[r] - bf_f(hb));
        }
        bf16x8 pfh = *(const bf16x8*)(PtH + key * 40 + quad * 8);
        bf16x8 pfl = *(const bf16x8*)(PtL + key * 40 + quad * 8);
        __builtin_amdgcn_s_setprio(1);
        #pragma unroll
        for (int nt = 0; nt < 4; nt++) {
            bf16x8 vf = *(const bf16x8*)(Vt_h + vbase + (long)nt * 16 * 2048
                                         + cb + quad * 8);
            Ont[nt] = __builtin_amdgcn_mfma_f32_16x16x32_bf16(pfh, vf, Ont[nt], 0, 0, 0);
            Ont[nt] = __builtin_amdgcn_mfma_f32_16x16x32_bf16(pfl, vf, Ont[nt], 0, 0, 0);
        }
        __builtin_amdgcn_s_setprio(0);
    }

    if (key == 0) {
        #pragma unroll
        for (int r = 0; r < 4; r++)
            ml[(rh * 2 + hs) * 16 + quad * 4 + r] = make_float2(mrow[r], lrow[r]);
    }
    __syncthreads();
    #pragma unroll
    for (int nt = 0; nt < 4; nt++)
        #pragma unroll
        for (int r = 0; r < 4; r++)
            Opart[rh * 2048 + (quad * 4 + r) * 128 + hs * 64 + nt * 16 + key] = Ont[nt][r];

    if (t < 32) {
        int q = t >> 1, hs2 = t & 1;
        float2 a = ml[(0 * 2 + hs2) * 16 + q];
        float2 c = ml[(1 * 2 + hs2) * 16 + q];
        float M = fmaxf(a.x, c.x);
        float w0 = __expf(a.x - M), w1 = __expf(c.x - M);
        float inv = 1.0f / fmaxf(a.y * w0 + c.y * w1, 1e-37f);
        sc[hs2 * 16 + q] = make_float2(w0 * inv, w1 * inv);
    }
    __syncthreads();

    if (t < 128) {
        int d = t, hs2 = d >> 6;
        float s = 0.f;
        #pragma unroll
        for (int q = 0; q < 16; q++) {
            float2 w = sc[hs2 * 16 + q];
            s += Opart[q * 128 + d] * w.x + Opart[2048 + q * 128 + d] * w.y;
        }
        atomicAdd(&pooledZ[b * P_DIM + h0 * HD + d], s);
    }
}

// ---------------- K_tail (cooperative): opool -> fc1 -> LN/gelu -> fc2 ------
// One cooperative launch (448,2)x256 replaces 4 kernels; grid.sync() between
// stages instead of full kernel drains. Stage bodies are verbatim copies of
// the previous k_gemv_opool / k_gemv_fc1 / k_exp_ln / k_gemv_fc2 -> identical
// numerics. 896 blocks x 256 thr x ~7.2KB LDS trivially co-resident.
__global__ __launch_bounds__(256) void k_tailco(
        const float* __restrict__ pooledZ,
        const float* __restrict__ outWT, const float* __restrict__ outb,
        const float* __restrict__ w1T,
        const float* __restrict__ b1_0, const float* __restrict__ b1_1,
        const float* __restrict__ b1_2,
        const float* __restrict__ g_0,  const float* __restrict__ bb_0,
        const float* __restrict__ g_1,  const float* __restrict__ bb_1,
        const float* __restrict__ g_2,  const float* __restrict__ bb_2,
        const float* __restrict__ w2T,
        const float* __restrict__ b2_0, const float* __restrict__ b2_1,
        const float* __restrict__ b2_2,
        float* __restrict__ pooled, float* __restrict__ h,
        float* __restrict__ out) {
    cooperative_groups::grid_group gg = cooperative_groups::this_grid();
    __shared__ float buf[1792];
    __shared__ float sm4[4];
    int bx = blockIdx.x, b = blockIdx.y, t = threadIdx.x;
    int lane = t & 63, w = t >> 6;

    // stage 1: opool (128 blocks per batch)
    if (bx < 128) {
        buf[t]       = pooledZ[b * P_DIM + t];
        buf[t + 256] = pooledZ[b * P_DIM + t + 256];
        __syncthreads();
        int c = bx * 4 + w;
        const float* wp = outWT + (long)c * 512;
        float acc = 0.f;
        #pragma unroll
        for (int i = 0; i < 8; i++) acc = fmaf(buf[lane + i * 64], wp[lane + i * 64], acc);
        acc = wave_sum(acc);
        if (lane == 0) pooled[b * P_DIM + c] = acc + (float)S_LEN * outb[c];
    }
    gg.sync();

    // stage 2: fc1 (all 448 blocks per batch)
    {
        buf[t]       = pooled[b * P_DIM + t]       * (1.0f / S_LEN);
        buf[t + 256] = pooled[b * P_DIM + t + 256] * (1.0f / S_LEN);
        __syncthreads();
        int c = bx * 4 + w;                // [0, 1792)
        const float* wp = w1T + (long)c * 512;
        float acc = 0.f;
        #pragma unroll
        for (int i = 0; i < 8; i++) acc = fmaf(buf[lane + i * 64], wp[lane + i * 64], acc);
        acc = wave_sum(acc);
        if (lane == 0) {
            float bb = (c < 256) ? b1_0[c] : (c < 768) ? b1_1[c - 256] : b1_2[c - 768];
            h[(long)b * 1792 + c] = acc + bb;
        }
    }
    gg.sync();

    // stage 3: LN + gelu per expert (3 blocks per batch)
    if (bx < 3) {
        int e = bx;
        const int offs[3] = {0, 256, 768};
        const int ns[3]   = {256, 512, 1024};
        const float* gs[3]  = {g_0, g_1, g_2};
        const float* bbs[3] = {bb_0, bb_1, bb_2};
        int n = ns[e];
        float* hp = h + (long)b * 1792 + offs[e];
        const float* g = gs[e]; const float* bb = bbs[e];

        float x[4];
        float loc = 0.f;
        for (int u = 0; u < 4; u++) {
            int j = t + u * 256;
            x[u] = (j < n) ? hp[j] : 0.f;
            loc += x[u];
        }
        float mu = block_reduce_sum(loc, sm4) / (float)n;
        loc = 0.f;
        for (int u = 0; u < 4; u++) {
            int j = t + u * 256;
            if (j < n) { float d = x[u] - mu; loc += d * d; }
        }
        float var = block_reduce_sum(loc, sm4) / (float)n;
        float rs = 1.0f / sqrtf(var + 1e-5f);
        for (int u = 0; u < 4; u++) {
            int j = t + u * 256;
            if (j < n) hp[j] = gelu_exact((x[u] - mu) * rs * g[j] + bb[j]);
        }
    }
    gg.sync();

    // stage 4: fc2 (224 blocks per batch)
    if (bx < 224) {
        for (int u = 0; u < 7; u++) buf[t + u * 256] = h[(long)b * 1792 + t + u * 256];
        __syncthreads();
        int c = bx * 4 + w;                // [0, 896)
        const float* wp; const float* hp2; int s2; float bb;
        if (c < 128)      { wp = w2T + (long)c * 256;                  hp2 = buf;       s2 = 256;  bb = b2_0[c]; }
        else if (c < 384) { wp = w2T + 32768 + (long)(c - 128) * 512;  hp2 = buf + 256; s2 = 512;  bb = b2_1[c - 128]; }
        else              { wp = w2T + 163840 + (long)(c - 384) * 1024; hp2 = buf + 768; s2 = 1024; bb = b2_2[c - 384]; }
        float acc = 0.f;
        for (int i = lane; i < s2; i += 64) acc = fmaf(hp2[i], wp[i], acc);
        acc = wave_sum(acc);
        if (lane == 0) out[b * 896 + c] = acc + bb;
    }
}

// ---------------------------------------------------------------------------
extern "C" void kernel_launch(void* const* d_in, const int* in_sizes, int n_in,
                              void* d_out, int out_size, void* d_ws, size_t ws_size,
                              hipStream_t stream) {
    const float* seq   = (const float*)d_in[0];
    const float* penta = (const float*)d_in[1];
    const float* spos  = (const float*)d_in[2];
    const float* projW = (const float*)d_in[3];
    const float* projb = (const float*)d_in[4];
    const float* lng   = (const float*)d_in[5];
    const float* lnb   = (const float*)d_in[6];
    const float* qkvW  = (const float*)d_in[7];
    const float* qkvb  = (const float*)d_in[8];
    const float* outW  = (const float*)d_in[9];
    const float* outb  = (const float*)d_in[10];

    float* ws      = (float*)d_ws;
    float* z_pre   = ws;                      // 2097152 floats (Ks alias)
    short* z_h     = (short*)(z_pre + 2097152); // 2097152 shorts
    short* z_l     = z_h + 2097152;           // 2097152 shorts
    float* qkv     = (float*)(z_l + 2097152); // 6291456 floats (seq-split alias)
    float* pooledZ = qkv + 6291456;           // 1024
    float* pooled  = pooledZ + 4096;          // 1024
    float* hbuf    = pooled + 1024;           // 4096
    unsigned long long* rowkey = (unsigned long long*)(hbuf + 4096);  // 4096 ull
    float* pos_srt = (float*)(rowkey + 4096); // 4096
    int*   order   = (int*)(pos_srt + 4096);  // 4096
    uint2* bounds  = (uint2*)(order + 4096);  // 4096 uint2
    unsigned long long* bmG = (unsigned long long*)(bounds + 4096); // 131072 ull
    short* cent_h  = (short*)(bmG + 131072);  // 524288 shorts
    short* cent_l  = cent_h + 524288;
    short* pjWT_h  = cent_l + 524288;         // 512x1024
    short* pjWT_l  = pjWT_h + 524288;
    short* qkWT_h  = pjWT_l + 524288;         // 1536x512
    short* qkWT_l  = qkWT_h + 786432;
    float* outWT   = (float*)(qkWT_l + 786432); // 262144 floats
    float* w1T     = outWT + 262144;          // 1792x512 = 917504 floats
    float* w2T     = w1T + 917504;            // 688128 floats

    // Aliases of dead regions (same as R3-R9):
    short* seq_h = (short*)qkv;               // 4096 x 1024
    short* seq_l = seq_h + 4194304;
    short* Ks_h = (short*)z_pre;              // 2 x 2048 x 512
    short* Ks_l = Ks_h + 2097152;
    short* Vt_h = cent_h;                     // 2 x 512 x 2048

    // fused prep: cent + wt(proj) + wt(qkv) + seq split + tail-W transposes
    k_prep<<<2824, 256, 0, stream>>>(penta, cent_h, cent_l,
                                     projW, pjWT_h, pjWT_l,
                                     qkvW, qkWT_h, qkWT_l,
                                     seq, seq_h, seq_l,
                                     rowkey, pooledZ,
                                     outW, outWT,
                                     (const float*)d_in[11],
                                     (const float*)d_in[17],
                                     (const float*)d_in[23], w1T,
                                     (const float*)d_in[15],
                                     (const float*)d_in[21],
                                     (const float*)d_in[27], w2T);

    // proj -> ln/gelu/norm (emits pre-split z)
    { dim3 g(64, 4);  k_mm<64, IN_DIM, P_DIM, 0><<<g, 256, 0, stream>>>(
          seq_h, seq_l, pjWT_h, pjWT_l, projb, z_pre, nullptr); }
    k_ln_gelu_norm<<<4096, 256, 0, stream>>>(z_pre, lng, lnb, z_h, z_l);

    // FUSED anchor + qkv GEMM (BM=64 -> 1280 blocks, 48KB LDS -> 3/CU)
    { dim3 g(64, 20); k_mmz<<<g, 256, 0, stream>>>(
          z_h, z_l, cent_h, cent_l, qkWT_h, qkWT_l, qkvb, qkv, rowkey); }

    // rank sort -> fused routes + K/V prep -> attention (pools directly)
    { dim3 g(8, 2);   k_rank<<<g, 256, 0, stream>>>(rowkey, spos, order, pos_srt); }
    k_routeskv<<<2048, 256, 0, stream>>>(pos_srt, order, bmG, bounds,
                                         qkv, Ks_h, Ks_l, Vt_h);
    k_attn<<<1024, 256, 0, stream>>>(qkv, order, bmG, bounds,
                                     Ks_h, Ks_l, Vt_h, pooledZ);

    // cooperative fused tail: opool -> fc1 -> LN/gelu -> fc2 (one launch)
    {
        const float* b1_0 = (const float*)d_in[12];
        const float* b1_1 = (const float*)d_in[18];
        const float* b1_2 = (const float*)d_in[24];
        const float* g_0  = (const float*)d_in[13];
        const float* bb_0 = (const float*)d_in[14];
        const float* g_1  = (const float*)d_in[19];
        const float* bb_1 = (const float*)d_in[20];
        const float* g_2  = (const float*)d_in[25];
        const float* bb_2 = (const float*)d_in[26];
        const float* b2_0 = (const float*)d_in[16];
        const float* b2_1 = (const float*)d_in[22];
        const float* b2_2 = (const float*)d_in[28];
        float* outp = (float*)d_out;
        const float* pooledZc = pooledZ;
        const float* outWTc = outWT;
        const float* w1Tc = w1T;
        const float* w2Tc = w2T;
        void* args[] = {
            (void*)&pooledZc, (void*)&outWTc, (void*)&outb,
            (void*)&w1Tc, (void*)&b1_0, (void*)&b1_1, (void*)&b1_2,
            (void*)&g_0, (void*)&bb_0, (void*)&g_1, (void*)&bb_1,
            (void*)&g_2, (void*)&bb_2,
            (void*)&w2Tc, (void*)&b2_0, (void*)&b2_1, (void*)&b2_2,
            (void*)&pooled, (void*)&hbuf, (void*)&outp };
        hipLaunchCooperativeKernel((void*)k_tailco, dim3(448, 2), dim3(256),
                                   args, 0, stream);
    }
}

// Round 11
// 321.733 us; speedup vs baseline: 2.0350x; 2.0350x over previous
//
#include <hip/hip_runtime.h>
#include <math.h>

#define DEV __device__ __forceinline__

static constexpr int S_LEN  = 2048;
static constexpr int IN_DIM = 1024;
static constexpr int P_DIM  = 512;
static constexpr int NHEAD  = 8;
static constexpr int HD     = 64;
static constexpr int KN     = 128;

typedef __attribute__((ext_vector_type(8))) short bf16x8;
typedef __attribute__((ext_vector_type(4))) float f32x4;

DEV float gelu_exact(float x) {
    return 0.5f * x * (1.0f + erff(x * 0.70710678118654752440f));
}

// float -> bf16 (RNE), and the split residual helpers
DEV short bf_hi(float x) {
    unsigned u = __float_as_uint(x);
    unsigned r = (u + 0x7fffu + ((u >> 16) & 1u)) >> 16;
    return (short)r;
}
DEV float bf_f(short h) { return __uint_as_float(((unsigned)(unsigned short)h) << 16); }

// 256-thread block sum reduction. sm4 must be float[4] shared.
DEV float block_reduce_sum(float v, float* sm4) {
    #pragma unroll
    for (int off = 32; off; off >>= 1) v += __shfl_down(v, off, 64);
    int lane = threadIdx.x & 63, w = threadIdx.x >> 6;
    __syncthreads();
    if (lane == 0) sm4[w] = v;
    __syncthreads();
    return sm4[0] + sm4[1] + sm4[2] + sm4[3];
}

// wave-wide sum, deterministic butterfly
DEV float wave_sum(float v) {
    #pragma unroll
    for (int off = 32; off; off >>= 1) v += __shfl_xor(v, off, 64);
    return v;
}

// ---------------- K_prep: fused cent + weight transposes + seq split --------
DEV void wt_body(const float* __restrict__ W, short* __restrict__ WTh,
                 short* __restrict__ WTl, int K, int N, int bk, int bn,
                 float (*tile)[65]) {
    int t = threadIdx.x;
    int c = t & 63, r4 = t >> 6;
    #pragma unroll
    for (int i = 0; i < 16; i++) {
        int row = r4 + i * 4;
        tile[row][c] = W[(long)(bk * 64 + row) * N + bn * 64 + c];
    }
    __syncthreads();
    #pragma unroll
    for (int i = 0; i < 16; i++) {
        int n = r4 + i * 4;
        float v = tile[c][n];
        short h = bf_hi(v);
        long o = (long)(bn * 64 + n) * K + bk * 64 + c;
        WTh[o] = h;
        WTl[o] = bf_hi(v - bf_f(h));
    }
}

DEV void t32_body(const float* __restrict__ W, float* __restrict__ WT,
                  int K, int N, int bk, int bn, float (*tile)[65]) {
    int t = threadIdx.x;
    int c = t & 63, r4 = t >> 6;
    #pragma unroll
    for (int i = 0; i < 16; i++) {
        int row = r4 + i * 4;
        tile[row][c] = W[(long)(bk * 64 + row) * N + bn * 64 + c];
    }
    __syncthreads();
    #pragma unroll
    for (int i = 0; i < 16; i++) {
        int n = r4 + i * 4;
        WT[(long)(bn * 64 + n) * K + bk * 64 + c] = tile[c][n];
    }
}

__global__ __launch_bounds__(256) void k_prep(const float* __restrict__ penta,
                                              short* __restrict__ ch, short* __restrict__ cl,
                                              const float* __restrict__ projW,
                                              short* __restrict__ pjh, short* __restrict__ pjl,
                                              const float* __restrict__ qkvW,
                                              short* __restrict__ qkh, short* __restrict__ qkl,
                                              const float* __restrict__ seq,
                                              short* __restrict__ sh, short* __restrict__ sl,
                                              unsigned long long* __restrict__ rowkey,
                                              float* __restrict__ pooledZ,
                                              const float* __restrict__ outW, float* __restrict__ outWT,
                                              const float* __restrict__ w1_0,
                                              const float* __restrict__ w1_1,
                                              const float* __restrict__ w1_2, float* __restrict__ w1T,
                                              const float* __restrict__ w2_0,
                                              const float* __restrict__ w2_1,
                                              const float* __restrict__ w2_2, float* __restrict__ w2T) {
    __shared__ float tile[64][65];
    __shared__ float sm4[4];
    int blk = blockIdx.x, t = threadIdx.x;
    if (blk < 1024) {
        int p = blk;
        if (t < 4) rowkey[p * 4 + t] = 0ull;
        if (p < 4) pooledZ[p * 256 + t] = 0.f;
        float c0 = 0.f, c1 = 0.f;
        #pragma unroll
        for (int v = 0; v < 5; v++) {
            const float* row = penta + ((long)p * 5 + v) * P_DIM;
            c0 += row[t];
            c1 += row[t + 256];
        }
        c0 /= 5.0f; c1 /= 5.0f;
        float tot = block_reduce_sum(c0 * c0 + c1 * c1, sm4);
        float n = fmaxf(sqrtf(tot), 1e-12f);
        float v0 = c0 / n, v1 = c1 / n;
        short h0 = bf_hi(v0), h1 = bf_hi(v1);
        ch[p * P_DIM + t]       = h0;
        ch[p * P_DIM + t + 256] = h1;
        cl[p * P_DIM + t]       = bf_hi(v0 - bf_f(h0));
        cl[p * P_DIM + t + 256] = bf_hi(v1 - bf_f(h1));
    } else if (blk < 1152) {
        int id = blk - 1024;                 // 16 x 8
        wt_body(projW, pjh, pjl, IN_DIM, P_DIM, id & 15, id >> 4, tile);
    } else if (blk < 1344) {
        int id = blk - 1152;                 // 8 x 24
        wt_body(qkvW, qkh, qkl, P_DIM, 3 * P_DIM, id & 7, id >> 3, tile);
    } else if (blk < 2368) {
        long base = ((long)(blk - 1344) * 256 + t) * 16;
        #pragma unroll
        for (int u = 0; u < 4; u++) {
            float4 v = *(const float4*)(seq + base + u * 4);
            short h0 = bf_hi(v.x), h1 = bf_hi(v.y), h2 = bf_hi(v.z), h3 = bf_hi(v.w);
            *(short4*)(sh + base + u * 4) = make_short4(h0, h1, h2, h3);
            *(short4*)(sl + base + u * 4) =
                make_short4(bf_hi(v.x - bf_f(h0)), bf_hi(v.y - bf_f(h1)),
                            bf_hi(v.z - bf_f(h2)), bf_hi(v.w - bf_f(h3)));
        }
    } else if (blk < 2432) {
        int id = blk - 2368;                 // outW 512x512: 8x8
        t32_body(outW, outWT, 512, 512, id & 7, id >> 3, tile);
    } else if (blk < 2464) {
        int id = blk - 2432;                 // w1_0 512x256 -> rows [0,256)
        t32_body(w1_0, w1T, 512, 256, id & 7, id >> 3, tile);
    } else if (blk < 2528) {
        int id = blk - 2464;                 // w1_1 512x512 -> rows [256,768)
        t32_body(w1_1, w1T + 256 * 512, 512, 512, id & 7, id >> 3, tile);
    } else if (blk < 2656) {
        int id = blk - 2528;                 // w1_2 512x1024 -> rows [768,1792)
        t32_body(w1_2, w1T + 768 * 512, 512, 1024, id & 7, id >> 3, tile);
    } else if (blk < 2664) {
        int id = blk - 2656;                 // w2_0 256x128
        t32_body(w2_0, w2T, 256, 128, id & 3, id >> 2, tile);
    } else if (blk < 2696) {
        int id = blk - 2664;                 // w2_1 512x256
        t32_body(w2_1, w2T + 32768, 512, 256, id & 7, id >> 3, tile);
    } else {
        int id = blk - 2696;                 // w2_2 1024x512
        t32_body(w2_2, w2T + 163840, 1024, 512, id & 15, id >> 4, tile);
    }
}

// ---------------- MFMA split-bf16 GEMM: C = A@W + bias ----------------------
// BM x 128 block tile, BK=64, 4 waves in 2x2, wave tile (BM/2) x 64.
template <int BM, int K, int N, int EPI>
__global__ __launch_bounds__(256) void k_mm(const short* __restrict__ Ash,
                                            const short* __restrict__ Asl,
                                            const short* __restrict__ BTh,
                                            const short* __restrict__ BTl,
                                            const float* __restrict__ bias,
                                            float* __restrict__ C,
                                            unsigned long long* __restrict__ rowkey) {
    constexpr int TI  = BM / 32;      // i-tiles (of 16 rows) per wave
    constexpr int CA  = BM / 8;       // 1KB staging chunks per A array
    constexpr int NCH = 2 * CA + 32;  // + 16 chunks each for Bh, Bl
    __shared__ __align__(128) short AhS[BM * 64], AlS[BM * 64];
    __shared__ __align__(128) short BhS[128 * 64], BlS[128 * 64];
    int t = threadIdx.x;
    int lane = t & 63, wave = t >> 6;
    int wr = (wave >> 1) * (BM / 2), wc = (wave & 1) * 64;
    int m = lane & 15, quad = lane >> 4;
    int rb = blockIdx.x * BM, cb = blockIdx.y * 128;
    int r8 = lane >> 3, p8 = lane & 7;
    int sl = p8 ^ r8;                 // pre-swizzled 16B source slot

    f32x4 acc[TI][4];
    #pragma unroll
    for (int i = 0; i < TI; i++)
        #pragma unroll
        for (int j = 0; j < 4; j++) acc[i][j] = (f32x4){0.f, 0.f, 0.f, 0.f};

    for (int k0 = 0; k0 < K; k0 += 64) {
        __syncthreads();
        for (int c = wave; c < NCH; c += 4) {
            const short* src; short* dst;
            if (c < CA) {
                src = Ash + (long)(rb + c * 8 + r8) * K + k0 + sl * 8;
                dst = AhS + c * 512;
            } else if (c < 2 * CA) {
                int cc = c - CA;
                src = Asl + (long)(rb + cc * 8 + r8) * K + k0 + sl * 8;
                dst = AlS + cc * 512;
            } else if (c < 2 * CA + 16) {
                int cc = c - 2 * CA;
                src = BTh + (long)(cb + cc * 8 + r8) * K + k0 + sl * 8;
                dst = BhS + cc * 512;
            } else {
                int cc = c - 2 * CA - 16;
                src = BTl + (long)(cb + cc * 8 + r8) * K + k0 + sl * 8;
                dst = BlS + cc * 512;
            }
            __builtin_amdgcn_global_load_lds(
                (const __attribute__((address_space(1))) unsigned int*)src,
                (__attribute__((address_space(3))) unsigned int*)dst, 16, 0, 0);
        }
        __syncthreads();

        #pragma unroll
        for (int ks = 0; ks < 2; ks++) {
            int so = ((ks * 4 + quad) ^ (m & 7)) * 8;
            bf16x8 ah[TI], al[TI], bh[4], bl[4];
            #pragma unroll
            for (int i = 0; i < TI; i++) {
                int off = (wr + i * 16 + m) * 64 + so;
                ah[i] = *(const bf16x8*)(AhS + off);
                al[i] = *(const bf16x8*)(AlS + off);
            }
            #pragma unroll
            for (int j = 0; j < 4; j++) {
                int off = (wc + j * 16 + m) * 64 + so;
                bh[j] = *(const bf16x8*)(BhS + off);
                bl[j] = *(const bf16x8*)(BlS + off);
            }
            #pragma unroll
            for (int i = 0; i < TI; i++)
                #pragma unroll
                for (int j = 0; j < 4; j++) {
                    acc[i][j] = __builtin_amdgcn_mfma_f32_16x16x32_bf16(ah[i], bh[j], acc[i][j], 0, 0, 0);
                    acc[i][j] = __builtin_amdgcn_mfma_f32_16x16x32_bf16(ah[i], bl[j], acc[i][j], 0, 0, 0);
                    acc[i][j] = __builtin_amdgcn_mfma_f32_16x16x32_bf16(al[i], bh[j], acc[i][j], 0, 0, 0);
                }
        }
    }

    if (EPI == 0) {
        #pragma unroll
        for (int i = 0; i < TI; i++) {
            int gr0 = rb + wr + i * 16 + quad * 4;
            #pragma unroll
            for (int j = 0; j < 4; j++) {
                int gc = cb + wc + j * 16 + m;
                float bv = bias[gc];
                #pragma unroll
                for (int r = 0; r < 4; r++)
                    C[(long)(gr0 + r) * N + gc] = acc[i][j][r] + bv;
            }
        }
    } else {
        #pragma unroll
        for (int i = 0; i < TI; i++) {
            #pragma unroll
            for (int r = 0; r < 4; r++) {
                int gr = rb + wr + i * 16 + quad * 4 + r;
                float bv = acc[i][0][r];
                int bp = cb + wc + m;
                #pragma unroll
                for (int j = 1; j < 4; j++) {
                    float v = acc[i][j][r];
                    int p = cb + wc + j * 16 + m;
                    if (v > bv) { bv = v; bp = p; }
                }
                #pragma unroll
                for (int off = 1; off < 16; off <<= 1) {
                    float ov = __shfl_xor(bv, off, 64);
                    int op = __shfl_xor(bp, off, 64);
                    if (ov > bv || (ov == bv && op < bp)) { bv = ov; bp = op; }
                }
                if (m == 0) {
                    unsigned u = __float_as_uint(bv);
                    u = (u & 0x80000000u) ? ~u : (u | 0x80000000u);
                    unsigned long long key =
                        ((unsigned long long)u << 32) | (unsigned)(0xFFFFFFFFu - (unsigned)bp);
                    atomicMax(&rowkey[gr], key);
                }
            }
        }
    }
}

// ---------------- K4: FUSED anchor + qkv GEMM (BM=64, 1280 blocks) ----------
__global__ __launch_bounds__(256) void k_mmz(const short* __restrict__ Ash,
                                             const short* __restrict__ Asl,
                                             const short* __restrict__ Ch,
                                             const short* __restrict__ Cl,
                                             const short* __restrict__ Qh,
                                             const short* __restrict__ Ql,
                                             const float* __restrict__ bias,
                                             float* __restrict__ C,
                                             unsigned long long* __restrict__ rowkey) {
    constexpr int BM = 64, K = 512;
    constexpr int TI  = BM / 32;
    constexpr int CA  = BM / 8;
    constexpr int NCH = 2 * CA + 32;
    __shared__ __align__(128) short AhS[BM * 64], AlS[BM * 64];
    __shared__ __align__(128) short BhS[128 * 64], BlS[128 * 64];
    int t = threadIdx.x;
    int lane = t & 63, wave = t >> 6;
    int wr = (wave >> 1) * (BM / 2), wc = (wave & 1) * 64;
    int m = lane & 15, quad = lane >> 4;
    bool anchor = blockIdx.y < 8;
    const short* BTh = anchor ? Ch : Qh;
    const short* BTl = anchor ? Cl : Ql;
    int rb = blockIdx.x * BM;
    int cb = (anchor ? blockIdx.y : (blockIdx.y - 8)) * 128;
    int r8 = lane >> 3, p8 = lane & 7;
    int sl = p8 ^ r8;

    f32x4 acc[TI][4];
    #pragma unroll
    for (int i = 0; i < TI; i++)
        #pragma unroll
        for (int j = 0; j < 4; j++) acc[i][j] = (f32x4){0.f, 0.f, 0.f, 0.f};

    for (int k0 = 0; k0 < K; k0 += 64) {
        __syncthreads();
        for (int c = wave; c < NCH; c += 4) {
            const short* src; short* dst;
            if (c < CA) {
                src = Ash + (long)(rb + c * 8 + r8) * K + k0 + sl * 8;
                dst = AhS + c * 512;
            } else if (c < 2 * CA) {
                int cc = c - CA;
                src = Asl + (long)(rb + cc * 8 + r8) * K + k0 + sl * 8;
                dst = AlS + cc * 512;
            } else if (c < 2 * CA + 16) {
                int cc = c - 2 * CA;
                src = BTh + (long)(cb + cc * 8 + r8) * K + k0 + sl * 8;
                dst = BhS + cc * 512;
            } else {
                int cc = c - 2 * CA - 16;
                src = BTl + (long)(cb + cc * 8 + r8) * K + k0 + sl * 8;
                dst = BlS + cc * 512;
            }
            __builtin_amdgcn_global_load_lds(
                (const __attribute__((address_space(1))) unsigned int*)src,
                (__attribute__((address_space(3))) unsigned int*)dst, 16, 0, 0);
        }
        __syncthreads();

        #pragma unroll
        for (int ks = 0; ks < 2; ks++) {
            int so = ((ks * 4 + quad) ^ (m & 7)) * 8;
            bf16x8 ah[TI], al[TI], bh[4], bl[4];
            #pragma unroll
            for (int i = 0; i < TI; i++) {
                int off = (wr + i * 16 + m) * 64 + so;
                ah[i] = *(const bf16x8*)(AhS + off);
                al[i] = *(const bf16x8*)(AlS + off);
            }
            #pragma unroll
            for (int j = 0; j < 4; j++) {
                int off = (wc + j * 16 + m) * 64 + so;
                bh[j] = *(const bf16x8*)(BhS + off);
                bl[j] = *(const bf16x8*)(BlS + off);
            }
            #pragma unroll
            for (int i = 0; i < TI; i++)
                #pragma unroll
                for (int j = 0; j < 4; j++) {
                    acc[i][j] = __builtin_amdgcn_mfma_f32_16x16x32_bf16(ah[i], bh[j], acc[i][j], 0, 0, 0);
                    acc[i][j] = __builtin_amdgcn_mfma_f32_16x16x32_bf16(ah[i], bl[j], acc[i][j], 0, 0, 0);
                    acc[i][j] = __builtin_amdgcn_mfma_f32_16x16x32_bf16(al[i], bh[j], acc[i][j], 0, 0, 0);
                }
        }
    }

    if (!anchor) {
        #pragma unroll
        for (int i = 0; i < TI; i++) {
            int gr0 = rb + wr + i * 16 + quad * 4;
            #pragma unroll
            for (int j = 0; j < 4; j++) {
                int gc = cb + wc + j * 16 + m;
                float bv = bias[gc];
                #pragma unroll
                for (int r = 0; r < 4; r++)
                    C[(long)(gr0 + r) * 1536 + gc] = acc[i][j][r] + bv;
            }
        }
    } else {
        #pragma unroll
        for (int i = 0; i < TI; i++) {
            #pragma unroll
            for (int r = 0; r < 4; r++) {
                int gr = rb + wr + i * 16 + quad * 4 + r;
                float bv = acc[i][0][r];
                int bp = cb + wc + m;
                #pragma unroll
                for (int j = 1; j < 4; j++) {
                    float v = acc[i][j][r];
                    int p = cb + wc + j * 16 + m;   // ascending; > keeps lowest p
                    if (v > bv) { bv = v; bp = p; }
                }
                #pragma unroll
                for (int off = 1; off < 16; off <<= 1) {
                    float ov = __shfl_xor(bv, off, 64);
                    int op = __shfl_xor(bp, off, 64);
                    if (ov > bv || (ov == bv && op < bp)) { bv = ov; bp = op; }
                }
                if (m == 0) {
                    unsigned u = __float_as_uint(bv);
                    u = (u & 0x80000000u) ? ~u : (u | 0x80000000u);
                    unsigned long long key =
                        ((unsigned long long)u << 32) | (unsigned)(0xFFFFFFFFu - (unsigned)bp);
                    atomicMax(&rowkey[gr], key);
                }
            }
        }
    }
}

// ---------------- K3: LayerNorm -> gelu -> L2 norm -> emit SPLIT bf16 -------
__global__ __launch_bounds__(256) void k_ln_gelu_norm(const float* __restrict__ Zin,
                                                      const float* __restrict__ g,
                                                      const float* __restrict__ b,
                                                      short* __restrict__ z_h,
                                                      short* __restrict__ z_l) {
    long row = blockIdx.x;
    int t = threadIdx.x;
    __shared__ float sm4[4];
    float x0 = Zin[row * P_DIM + t], x1 = Zin[row * P_DIM + t + 256];
    float mu = block_reduce_sum(x0 + x1, sm4) * (1.0f / P_DIM);
    float d0 = x0 - mu, d1 = x1 - mu;
    float var = block_reduce_sum(d0 * d0 + d1 * d1, sm4) * (1.0f / P_DIM);
    float rs = 1.0f / sqrtf(var + 1e-5f);
    float y0 = gelu_exact(d0 * rs * g[t] + b[t]);
    float y1 = gelu_exact(d1 * rs * g[t + 256] + b[t + 256]);
    float nn = block_reduce_sum(y0 * y0 + y1 * y1, sm4);
    float n = fmaxf(sqrtf(nn), 1e-12f);
    float v0 = y0 / n, v1 = y1 / n;
    short h0 = bf_hi(v0), h1 = bf_hi(v1);
    z_h[row * P_DIM + t]       = h0;
    z_h[row * P_DIM + t + 256] = h1;
    z_l[row * P_DIM + t]       = bf_hi(v0 - bf_f(h0));
    z_l[row * P_DIM + t + 256] = bf_hi(v1 - bf_f(h1));
}

// ---------------- K5: O(N^2) rank sort ---------------------------------------
__global__ __launch_bounds__(256) void k_rank(const unsigned long long* __restrict__ rowkey,
                                              const float* __restrict__ spos,
                                              int* __restrict__ order,
                                              float* __restrict__ pos_srt) {
    int b = blockIdx.y, t = threadIdx.x;
    __shared__ unsigned long long key[2048];
    for (int u = 0; u < 8; u++) {
        int i = t + u * 256;
        unsigned p = 0xFFFFFFFFu - (unsigned)(rowkey[b * 2048 + i] & 0xFFFFFFFFull);
        key[i] = (((unsigned long long)__float_as_uint(spos[p])) << 32) | (unsigned)i;
    }
    __syncthreads();
    int i = blockIdx.x * 256 + t;
    unsigned long long ki = key[i];
    int rank = 0;
    #pragma unroll 8
    for (int j = 0; j < 2048; j++) rank += (key[j] < ki) ? 1 : 0;
    order[b * 2048 + rank]   = i;
    pos_srt[b * 2048 + rank] = __uint_as_float((unsigned)(ki >> 32));
}

// ---------------- K6: FUSED routes (top-128 bitmap) + K/V prep ---------------
__global__ __launch_bounds__(256) void k_routeskv(const float* __restrict__ pos_srt,
                                                  const int* __restrict__ order,
                                                  unsigned long long* __restrict__ bmG,
                                                  uint2* __restrict__ bounds,
                                                  const float* __restrict__ qkv,
                                                  short* __restrict__ Ks_h,
                                                  short* __restrict__ Ks_l,
                                                  short* __restrict__ Vt_h) {
    __shared__ __align__(16) char smem[12288];
    int blk0 = blockIdx.x, t = threadIdx.x;
    if (blk0 < 1024) {
        float* ps = (float*)smem;                       // 2048 floats
        unsigned short* tk = (unsigned short*)(smem + 8192); // 2048 u16
        int blk = blk0;
        int b = blk >> 9;
        int lane = t & 63, wave = t >> 6;
        int r = (blk & 511) * 4 + wave;
        for (int u = 0; u < 8; u++) {
            int i = t + u * 256;
            ps[i] = pos_srt[b * 2048 + i];
            tk[i] = (unsigned short)order[b * 2048 + i];
        }
        __syncthreads();

        float pi = ps[r];
        float T = 3e38f;
        #pragma unroll
        for (int a2 = 0; a2 < 2; a2++) {
            int a = lane + a2 * 64;
            int jl = r - a, jr = r + 127 - a;
            if (jl >= 0 && jr <= 2047) {
                float dl = (a > 0)   ? (pi - ps[jl]) : 0.f;
                float dr = (a < 127) ? (ps[jr] - pi) : 0.f;
                T = fminf(T, fmaxf(dl, dr));
            }
        }
        #pragma unroll
        for (int off = 1; off < 64; off <<= 1) T = fminf(T, __shfl_xor(T, off, 64));

        int lo = 0, hi = r;
        while (lo < hi) { int mid = (lo + hi) >> 1; if (pi - ps[mid] <= T) hi = mid; else lo = mid + 1; }
        int mn = lo;
        lo = r; hi = 2047;
        while (lo < hi) { int mid = (lo + hi + 1) >> 1; if (ps[mid] - pi <= T) lo = mid; else hi = mid - 1; }
        int mx = lo;
        int Ls, Rs;
        if (T > 0.f) {
            lo = 0; hi = r;
            while (lo < hi) { int mid = (lo + hi) >> 1; if (pi - ps[mid] < T) hi = mid; else lo = mid + 1; }
            Ls = lo;
            lo = r; hi = 2047;
            while (lo < hi) { int mid = (lo + hi + 1) >> 1; if (ps[mid] - pi < T) lo = mid; else hi = mid - 1; }
            Rs = lo;
        } else { Ls = r + 1; Rs = r - 1; }

        int cnt_strict = (Rs >= Ls) ? (Rs - Ls + 1) : 0;
        int need = 128 - cnt_strict;
        int l0a, l0b, r0a, r0b;
        if (cnt_strict > 0) { l0a = mn; l0b = Ls - 1; r0a = Rs + 1; r0b = mx; }
        else                { l0a = mn; l0b = mx;     r0a = 1;      r0b = 0; }
        int nL = (l0b >= l0a) ? (l0b - l0a + 1) : 0;
        int nR = (r0b >= r0a) ? (r0b - r0a + 1) : 0;
        int tiecount = nL + nR;

        int X = 65535;
        if (need < tiecount) {
            int lo2 = 0, hi2 = 2047;
            while (lo2 < hi2) {
                int mid = (lo2 + hi2) >> 1;
                int cnt = 0;
                for (int e = lane; e < tiecount; e += 64) {
                    int j = (e < nL) ? (l0a + e) : (r0a + e - nL);
                    cnt += (tk[j] <= mid) ? 1 : 0;
                }
                #pragma unroll
                for (int off = 1; off < 64; off <<= 1) cnt += __shfl_xor(cnt, off, 64);
                if (cnt >= need) hi2 = mid; else lo2 = mid + 1;
            }
            X = lo2;
        }

        int qlo_loc = 1 << 30, qhi_loc = -1;
        if (lane < 32) {
            unsigned long long bits = 0;
            int j0 = lane << 6, j1 = j0 + 63;
            if (cnt_strict > 0) {
                int a0 = max(Ls, j0), a1 = min(Rs, j1);
                if (a0 <= a1) {
                    int s = a0 - j0, e = a1 - j0;
                    unsigned long long msk = (e - s == 63) ? ~0ull
                                           : (((1ull << (e - s + 1)) - 1) << s);
                    bits |= msk;
                }
            }
            int a0 = max(l0a, j0), a1 = min(l0b, j1);
            for (int j = a0; j <= a1; j++) if (tk[j] <= X) bits |= 1ull << (j - j0);
            a0 = max(r0a, j0); a1 = min(r0b, j1);
            for (int j = a0; j <= a1; j++) if (tk[j] <= X) bits |= 1ull << (j - j0);
            if (bits) {
                qlo_loc = j0 + __builtin_ctzll(bits);
                qhi_loc = j0 + 63 - __builtin_clzll(bits);
            }
            bmG[((long)(b * 2048 + r)) * 32 + lane] = bits;
        }
        #pragma unroll
        for (int off = 1; off < 64; off <<= 1) {
            qlo_loc = min(qlo_loc, __shfl_xor(qlo_loc, off, 64));
            qhi_loc = max(qhi_loc, __shfl_xor(qhi_loc, off, 64));
        }
        if (lane == 0)
            bounds[b * 2048 + r] = make_uint2((unsigned)qlo_loc, (unsigned)qhi_loc);
    } else if (blk0 < 1536) {
        int blk = blk0 - 1024;                 // K prep
        int b = blk >> 8, bx = blk & 255;
        int lr = t >> 5;
        int seg = t & 31;
        int rank = bx * 8 + lr;
        int tok = order[b * 2048 + rank];
        const float4* src = (const float4*)qkv + (long)(b * 2048 + tok) * 384 + 128 + seg * 4;
        long dsto = (long)(b * 2048 + rank) * 512 + seg * 16;
        #pragma unroll
        for (int u = 0; u < 4; u++) {
            float4 v = src[u];
            short h0 = bf_hi(v.x), h1 = bf_hi(v.y), h2 = bf_hi(v.z), h3 = bf_hi(v.w);
            *(short4*)(Ks_h + dsto + u * 4) = make_short4(h0, h1, h2, h3);
            *(short4*)(Ks_l + dsto + u * 4) =
                make_short4(bf_hi(v.x - bf_f(h0)), bf_hi(v.y - bf_f(h1)),
                            bf_hi(v.z - bf_f(h2)), bf_hi(v.w - bf_f(h3)));
        }
    } else {
        short (*tile)[72] = (short(*)[72])smem;   // 64 x 72 shorts = 9216 B
        int id = blk0 - 1536;                  // V prep
        int rt = id & 31, dt = (id >> 5) & 7, b = id >> 8;
        int lr = t >> 2;
        int q4 = t & 3;
        int tok = order[b * 2048 + rt * 64 + lr];
        const float4* src = (const float4*)qkv + (long)(b * 2048 + tok) * 384 + 256 + dt * 16;
        #pragma unroll
        for (int u = 0; u < 4; u++) {
            float4 v = src[q4 + u * 4];
            int d0 = (q4 + u * 4) * 4;
            tile[d0 + 0][lr] = bf_hi(v.x);
            tile[d0 + 1][lr] = bf_hi(v.y);
            tile[d0 + 2][lr] = bf_hi(v.z);
            tile[d0 + 3][lr] = bf_hi(v.w);
        }
        __syncthreads();
        int d = t >> 2, c4 = t & 3;
        long o = ((long)(b * 512 + dt * 64 + d)) * 2048 + rt * 64 + c4 * 16;
        #pragma unroll
        for (int j = 0; j < 4; j++)
            *(short4*)(Vt_h + o + j * 4) = make_short4(tile[d][c4 * 16 + j * 4 + 0],
                                                       tile[d][c4 * 16 + j * 4 + 1],
                                                       tile[d][c4 * 16 + j * 4 + 2],
                                                       tile[d][c4 * 16 + j * 4 + 3]);
    }
}

// ---------------- K7: MFMA flash attention (direct-global K/V) --------------
__global__ __launch_bounds__(256) void k_attn(const float* __restrict__ qkv,
                                              const int* __restrict__ order,
                                              const unsigned long long* __restrict__ bmG,
                                              const uint2* __restrict__ bounds,
                                              const short* __restrict__ Ks_h,
                                              const short* __restrict__ Ks_l,
                                              const short* __restrict__ Vt_h,
                                              float* __restrict__ pooledZ) {
    __shared__ __align__(16) char smem[17280];
    short* Pt = (short*)smem;                               // 4 waves x 1280 shorts
    unsigned short* cm = (unsigned short*)(smem + 10240);   // 128 x 16
    float* Opart = (float*)smem;                            // alias: [2][16][128]
    float2* ml = (float2*)(smem + 16384);                   // [2][2][16]
    int* sh_tok = (int*)(smem + 16896);                     // 16
    int* sh_lohi = (int*)(smem + 16960);                    // 2
    float2* sc = (float2*)(smem + 16968);                   // [2][16] w0*inv, w1*inv

    int gb = blockIdx.x;
    int b  = gb >> 9;
    int qg = (gb >> 2) & 127;
    int hp = gb & 3;
    int h0 = hp * 2;
    int r0 = qg * 16;
    int t = threadIdx.x;
    int lane = t & 63, wave = t >> 6;
    int rh = wave & 1, hs = wave >> 1;
    int key = lane & 15, quad = lane >> 4;

    const float4* qkvF4 = (const float4*)qkv;

    if (t < 16) sh_tok[t] = order[b * 2048 + r0 + t];
    if (t == 0) { sh_lohi[0] = 1 << 30; sh_lohi[1] = 0; }
    #pragma unroll
    for (int u = 0; u < 8; u++) {
        int e = t + u * 256;
        int c = e >> 4, q = e & 15;
        cm[c * 16 + q] = (unsigned short)(
            (bmG[((long)(b * 2048 + r0 + q)) * 32 + (c >> 2)] >> ((c & 3) * 16)) & 0xFFFF);
    }
    __syncthreads();
    if (t < 16) {
        uint2 bd = bounds[b * 2048 + r0 + t];
        atomicMin(&sh_lohi[0], (int)bd.x);
        atomicMax(&sh_lohi[1], (int)bd.y);
    }

    bf16x8 qh[2], ql[2];
    {
        long tq = (long)(b * 2048 + sh_tok[key]) * 384;
        #pragma unroll
        for (int ks = 0; ks < 2; ks++) {
            float4 v0 = qkvF4[tq + (h0 + hs) * 16 + ks * 8 + quad * 2];
            float4 v1 = qkvF4[tq + (h0 + hs) * 16 + ks * 8 + quad * 2 + 1];
            float vv[8] = {v0.x, v0.y, v0.z, v0.w, v1.x, v1.y, v1.z, v1.w};
            #pragma unroll
            for (int j = 0; j < 8; j++) {
                short hb = bf_hi(vv[j]);
                qh[ks][j] = hb;
                ql[ks][j] = bf_hi(vv[j] - bf_f(hb));
            }
        }
    }
    __syncthreads();
    int lo = sh_lohi[0] & ~63, hi = sh_lohi[1] + 1;

    float mrow[4], lrow[4];
    f32x4 Ont[4];
    #pragma unroll
    for (int r = 0; r < 4; r++) { mrow[r] = -1e30f; lrow[r] = 0.f; }
    #pragma unroll
    for (int nt = 0; nt < 4; nt++) Ont[nt] = (f32x4){0.f, 0.f, 0.f, 0.f};

    short* PtH = Pt + wave * 1280;
    short* PtL = PtH + 640;

    int hd = h0 + hs;
    long kbase = ((long)b * 2048) * 512 + hd * 64 + quad * 8;
    long vbase = ((long)(b * 512 + hd * 64 + key)) * 2048;

    // NOTE: no __syncthreads() in this loop — waves run fully independently,
    // so s_setprio around the MFMA clusters pays (T5 / m191 regime).
    for (int c0 = lo; c0 < hi; c0 += 64) {
        int cb = c0 + rh * 32;
        if (cb >= hi) continue;
        int ch0 = cb >> 4;
        unsigned long long m0 = *(const unsigned long long*)(cm + ch0 * 16 + quad * 4);
        unsigned long long m1 = (ch0 + 1 < 128)
            ? *(const unsigned long long*)(cm + (ch0 + 1) * 16 + quad * 4) : 0ull;
        if (!__any((m0 | m1) != 0ull)) continue;

        long kr0 = kbase + (long)(cb + key) * 512;
        long kr1 = kbase + (long)(cb + 16 + key) * 512;

        f32x4 S0 = (f32x4){0.f,0.f,0.f,0.f}, S1 = (f32x4){0.f,0.f,0.f,0.f};
        __builtin_amdgcn_s_setprio(1);
        #pragma unroll
        for (int ks = 0; ks < 2; ks++) {
            bf16x8 b0h = *(const bf16x8*)(Ks_h + kr0 + ks * 32);
            bf16x8 b0l = *(const bf16x8*)(Ks_l + kr0 + ks * 32);
            bf16x8 b1h = *(const bf16x8*)(Ks_h + kr1 + ks * 32);
            bf16x8 b1l = *(const bf16x8*)(Ks_l + kr1 + ks * 32);
            S0 = __builtin_amdgcn_mfma_f32_16x16x32_bf16(qh[ks], b0h, S0, 0, 0, 0);
            S0 = __builtin_amdgcn_mfma_f32_16x16x32_bf16(qh[ks], b0l, S0, 0, 0, 0);
            S0 = __builtin_amdgcn_mfma_f32_16x16x32_bf16(ql[ks], b0h, S0, 0, 0, 0);
            S1 = __builtin_amdgcn_mfma_f32_16x16x32_bf16(qh[ks], b1h, S1, 0, 0, 0);
            S1 = __builtin_amdgcn_mfma_f32_16x16x32_bf16(qh[ks], b1l, S1, 0, 0, 0);
            S1 = __builtin_amdgcn_mfma_f32_16x16x32_bf16(ql[ks], b1h, S1, 0, 0, 0);
        }
        __builtin_amdgcn_s_setprio(0);
        float s0[4], s1[4], p0[4], p1[4];
        unsigned bit0[4], bit1[4];
        #pragma unroll
        for (int r = 0; r < 4; r++) {
            bit0[r] = (unsigned)((m0 >> (r * 16 + key)) & 1);
            bit1[r] = (unsigned)((m1 >> (r * 16 + key)) & 1);
            s0[r] = bit0[r] ? S0[r] * 0.125f : -1e30f;
            s1[r] = bit1[r] ? S1[r] * 0.125f : -1e30f;
        }
        #pragma unroll
        for (int r = 0; r < 4; r++) {
            float cmax = fmaxf(s0[r], s1[r]);
            cmax = fmaxf(cmax, __shfl_xor(cmax, 1, 64));
            cmax = fmaxf(cmax, __shfl_xor(cmax, 2, 64));
            cmax = fmaxf(cmax, __shfl_xor(cmax, 4, 64));
            cmax = fmaxf(cmax, __shfl_xor(cmax, 8, 64));
            float mn = fmaxf(mrow[r], cmax);
            float alpha = __expf(mrow[r] - mn);
            mrow[r] = mn;
            p0[r] = bit0[r] ? __expf(s0[r] - mn) : 0.f;
            p1[r] = bit1[r] ? __expf(s1[r] - mn) : 0.f;
            float rs = p0[r] + p1[r];
            rs += __shfl_xor(rs, 1, 64);
            rs += __shfl_xor(rs, 2, 64);
            rs += __shfl_xor(rs, 4, 64);
            rs += __shfl_xor(rs, 8, 64);
            lrow[r] = lrow[r] * alpha + rs;
            #pragma unroll
            for (int nt = 0; nt < 4; nt++) Ont[nt][r] *= alpha;
        }
        #pragma unroll
        for (int r = 0; r < 4; r++) {
            short ha = bf_hi(p0[r]);
            PtH[(quad * 4 + r) * 40 + key] = ha;
            PtL[(quad * 4 + r) * 40 + key] = bf_hi(p0[r] - bf_f(ha));
            short hb = bf_hi(p1[r]);
            PtH[(quad * 4 + r) * 40 + 16 + key] = hb;
            PtL[(quad * 4 + r) * 40 + 16 + key] = bf_hi(p1[r] - bf_f(hb));
        }
        bf16x8 pfh = *(const bf16x8*)(PtH + key * 40 + quad * 8);
        bf16x8 pfl = *(const bf16x8*)(PtL + key * 40 + quad * 8);
        __builtin_amdgcn_s_setprio(1);
        #pragma unroll
        for (int nt = 0; nt < 4; nt++) {
            bf16x8 vf = *(const bf16x8*)(Vt_h + vbase + (long)nt * 16 * 2048
                                         + cb + quad * 8);
            Ont[nt] = __builtin_amdgcn_mfma_f32_16x16x32_bf16(pfh, vf, Ont[nt], 0, 0, 0);
            Ont[nt] = __builtin_amdgcn_mfma_f32_16x16x32_bf16(pfl, vf, Ont[nt], 0, 0, 0);
        }
        __builtin_amdgcn_s_setprio(0);
    }

    if (key == 0) {
        #pragma unroll
        for (int r = 0; r < 4; r++)
            ml[(rh * 2 + hs) * 16 + quad * 4 + r] = make_float2(mrow[r], lrow[r]);
    }
    __syncthreads();
    #pragma unroll
    for (int nt = 0; nt < 4; nt++)
        #pragma unroll
        for (int r = 0; r < 4; r++)
            Opart[rh * 2048 + (quad * 4 + r) * 128 + hs * 64 + nt * 16 + key] = Ont[nt][r];

    if (t < 32) {
        int q = t >> 1, hs2 = t & 1;
        float2 a = ml[(0 * 2 + hs2) * 16 + q];
        float2 c = ml[(1 * 2 + hs2) * 16 + q];
        float M = fmaxf(a.x, c.x);
        float w0 = __expf(a.x - M), w1 = __expf(c.x - M);
        float inv = 1.0f / fmaxf(a.y * w0 + c.y * w1, 1e-37f);
        sc[hs2 * 16 + q] = make_float2(w0 * inv, w1 * inv);
    }
    __syncthreads();

    if (t < 128) {
        int d = t, hs2 = d >> 6;
        float s = 0.f;
        #pragma unroll
        for (int q = 0; q < 16; q++) {
            float2 w = sc[hs2 * 16 + q];
            s += Opart[q * 128 + d] * w.x + Opart[2048 + q * 128 + d] * w.y;
        }
        atomicAdd(&pooledZ[b * P_DIM + h0 * HD + d], s);
    }
}

// ---------------- tail GEMVs: one wave per output column (transposed W) -----
__global__ __launch_bounds__(256) void k_gemv_opool(const float* __restrict__ pooledZ,
                                                    const float* __restrict__ outWT,
                                                    const float* __restrict__ outb,
                                                    float* __restrict__ pooled) {
    int b = blockIdx.y, t = threadIdx.x;
    int lane = t & 63, w = t >> 6;
    __shared__ float pz[P_DIM];
    pz[t]       = pooledZ[b * P_DIM + t];
    pz[t + 256] = pooledZ[b * P_DIM + t + 256];
    __syncthreads();
    int c = blockIdx.x * 4 + w;
    const float* wp = outWT + (long)c * 512;
    float acc = 0.f;
    #pragma unroll
    for (int i = 0; i < 8; i++) acc = fmaf(pz[lane + i * 64], wp[lane + i * 64], acc);
    acc = wave_sum(acc);
    if (lane == 0) pooled[b * P_DIM + c] = acc + (float)S_LEN * outb[c];
}

__global__ __launch_bounds__(256) void k_gemv_fc1(const float* __restrict__ pooled,
                                                  const float* __restrict__ w1T,
                                                  const float* __restrict__ b1_0,
                                                  const float* __restrict__ b1_1,
                                                  const float* __restrict__ b1_2,
                                                  float* __restrict__ h) {
    int b = blockIdx.y, t = threadIdx.x;
    int lane = t & 63, w = t >> 6;
    __shared__ float pl[P_DIM];
    pl[t]       = pooled[b * P_DIM + t]       * (1.0f / S_LEN);
    pl[t + 256] = pooled[b * P_DIM + t + 256] * (1.0f / S_LEN);
    __syncthreads();
    int c = blockIdx.x * 4 + w;                // [0, 1792)
    const float* wp = w1T + (long)c * 512;
    float acc = 0.f;
    #pragma unroll
    for (int i = 0; i < 8; i++) acc = fmaf(pl[lane + i * 64], wp[lane + i * 64], acc);
    acc = wave_sum(acc);
    if (lane == 0) {
        float bb = (c < 256) ? b1_0[c] : (c < 768) ? b1_1[c - 256] : b1_2[c - 768];
        h[(long)b * 1792 + c] = acc + bb;
    }
}

__global__ __launch_bounds__(256) void k_gemv_fc2(const float* __restrict__ h,
                                                  const float* __restrict__ w2T,
                                                  const float* __restrict__ b2_0,
                                                  const float* __restrict__ b2_1,
                                                  const float* __restrict__ b2_2,
                                                  float* __restrict__ out) {
    int b = blockIdx.y, t = threadIdx.x;
    int lane = t & 63, w = t >> 6;
    __shared__ float hh[1792];
    for (int u = 0; u < 7; u++) hh[t + u * 256] = h[(long)b * 1792 + t + u * 256];
    __syncthreads();
    int c = blockIdx.x * 4 + w;                // [0, 896)
    const float* wp; const float* hp; int s2; float bb;
    if (c < 128)      { wp = w2T + (long)c * 256;                hp = hh;       s2 = 256;  bb = b2_0[c]; }
    else if (c < 384) { wp = w2T + 32768 + (long)(c - 128) * 512;  hp = hh + 256; s2 = 512;  bb = b2_1[c - 128]; }
    else              { wp = w2T + 163840 + (long)(c - 384) * 1024; hp = hh + 768; s2 = 1024; bb = b2_2[c - 384]; }
    float acc = 0.f;
    for (int i = lane; i < s2; i += 64) acc = fmaf(hp[i], wp[i], acc);
    acc = wave_sum(acc);
    if (lane == 0) out[b * 896 + c] = acc + bb;
}

// ---------------- Expert stage 2: LN + gelu per (expert, batch) -------------
__global__ __launch_bounds__(256) void k_exp_ln(float* __restrict__ h,
                                                const float* __restrict__ g0, const float* __restrict__ bb0,
                                                const float* __restrict__ g1, const float* __restrict__ bb1,
                                                const float* __restrict__ g2, const float* __restrict__ bb2) {
    int e = blockIdx.x, b = blockIdx.y, t = threadIdx.x;
    __shared__ float sm4[4];
    const int offs[3] = {0, 256, 768};
    const int ns[3]   = {256, 512, 1024};
    const float* gs[3]  = {g0, g1, g2};
    const float* bbs[3] = {bb0, bb1, bb2};
    int n = ns[e];
    float* hp = h + (long)b * 1792 + offs[e];
    const float* g = gs[e]; const float* bb = bbs[e];

    float x[4];
    float loc = 0.f;
    for (int u = 0; u < 4; u++) {
        int j = t + u * 256;
        x[u] = (j < n) ? hp[j] : 0.f;
        loc += x[u];
    }
    float mu = block_reduce_sum(loc, sm4) / (float)n;
    loc = 0.f;
    for (int u = 0; u < 4; u++) {
        int j = t + u * 256;
        if (j < n) { float d = x[u] - mu; loc += d * d; }
    }
    float var = block_reduce_sum(loc, sm4) / (float)n;
    float rs = 1.0f / sqrtf(var + 1e-5f);
    for (int u = 0; u < 4; u++) {
        int j = t + u * 256;
        if (j < n) hp[j] = gelu_exact((x[u] - mu) * rs * g[j] + bb[j]);
    }
}

// ---------------------------------------------------------------------------
extern "C" void kernel_launch(void* const* d_in, const int* in_sizes, int n_in,
                              void* d_out, int out_size, void* d_ws, size_t ws_size,
                              hipStream_t stream) {
    const float* seq   = (const float*)d_in[0];
    const float* penta = (const float*)d_in[1];
    const float* spos  = (const float*)d_in[2];
    const float* projW = (const float*)d_in[3];
    const float* projb = (const float*)d_in[4];
    const float* lng   = (const float*)d_in[5];
    const float* lnb   = (const float*)d_in[6];
    const float* qkvW  = (const float*)d_in[7];
    const float* qkvb  = (const float*)d_in[8];
    const float* outW  = (const float*)d_in[9];
    const float* outb  = (const float*)d_in[10];

    float* ws      = (float*)d_ws;
    float* z_pre   = ws;                      // 2097152 floats (Ks alias)
    short* z_h     = (short*)(z_pre + 2097152); // 2097152 shorts
    short* z_l     = z_h + 2097152;           // 2097152 shorts
    float* qkv     = (float*)(z_l + 2097152); // 6291456 floats (seq-split alias)
    float* pooledZ = qkv + 6291456;           // 1024
    float* pooled  = pooledZ + 4096;          // 1024
    float* hbuf    = pooled + 1024;           // 4096
    unsigned long long* rowkey = (unsigned long long*)(hbuf + 4096);  // 4096 ull
    float* pos_srt = (float*)(rowkey + 4096); // 4096
    int*   order   = (int*)(pos_srt + 4096);  // 4096
    uint2* bounds  = (uint2*)(order + 4096);  // 4096 uint2
    unsigned long long* bmG = (unsigned long long*)(bounds + 4096); // 131072 ull
    short* cent_h  = (short*)(bmG + 131072);  // 524288 shorts
    short* cent_l  = cent_h + 524288;
    short* pjWT_h  = cent_l + 524288;         // 512x1024
    short* pjWT_l  = pjWT_h + 524288;
    short* qkWT_h  = pjWT_l + 524288;         // 1536x512
    short* qkWT_l  = qkWT_h + 786432;
    float* outWT   = (float*)(qkWT_l + 786432); // 262144 floats
    float* w1T     = outWT + 262144;          // 1792x512 = 917504 floats
    float* w2T     = w1T + 917504;            // 688128 floats

    // Aliases of dead regions (same as R3-R9):
    short* seq_h = (short*)qkv;               // 4096 x 1024
    short* seq_l = seq_h + 4194304;
    short* Ks_h = (short*)z_pre;              // 2 x 2048 x 512
    short* Ks_l = Ks_h + 2097152;
    short* Vt_h = cent_h;                     // 2 x 512 x 2048

    // fused prep: cent + wt(proj) + wt(qkv) + seq split + tail-W transposes
    k_prep<<<2824, 256, 0, stream>>>(penta, cent_h, cent_l,
                                     projW, pjWT_h, pjWT_l,
                                     qkvW, qkWT_h, qkWT_l,
                                     seq, seq_h, seq_l,
                                     rowkey, pooledZ,
                                     outW, outWT,
                                     (const float*)d_in[11],
                                     (const float*)d_in[17],
                                     (const float*)d_in[23], w1T,
                                     (const float*)d_in[15],
                                     (const float*)d_in[21],
                                     (const float*)d_in[27], w2T);

    // proj -> ln/gelu/norm (emits pre-split z)
    { dim3 g(64, 4);  k_mm<64, IN_DIM, P_DIM, 0><<<g, 256, 0, stream>>>(
          seq_h, seq_l, pjWT_h, pjWT_l, projb, z_pre, nullptr); }
    k_ln_gelu_norm<<<4096, 256, 0, stream>>>(z_pre, lng, lnb, z_h, z_l);

    // FUSED anchor + qkv GEMM (BM=64 -> 1280 blocks, 48KB LDS -> 3/CU)
    { dim3 g(64, 20); k_mmz<<<g, 256, 0, stream>>>(
          z_h, z_l, cent_h, cent_l, qkWT_h, qkWT_l, qkvb, qkv, rowkey); }

    // rank sort -> fused routes + K/V prep -> attention (pools directly)
    { dim3 g(8, 2);   k_rank<<<g, 256, 0, stream>>>(rowkey, spos, order, pos_srt); }
    k_routeskv<<<2048, 256, 0, stream>>>(pos_srt, order, bmG, bounds,
                                         qkv, Ks_h, Ks_l, Vt_h);
    k_attn<<<1024, 256, 0, stream>>>(qkv, order, bmG, bounds,
                                     Ks_h, Ks_l, Vt_h, pooledZ);

    // tail: wave-per-column GEMVs on transposed weights (coalesced, parallel)
    { dim3 g(128, 2); k_gemv_opool<<<g, 256, 0, stream>>>(pooledZ, outWT, outb, pooled); }
    { dim3 g(448, 2); k_gemv_fc1<<<g, 256, 0, stream>>>(pooled, w1T,
        (const float*)d_in[12], (const float*)d_in[18], (const float*)d_in[24], hbuf); }
    { dim3 g(3, 2);   k_exp_ln<<<g, 256, 0, stream>>>(hbuf,
        (const float*)d_in[13], (const float*)d_in[14],
        (const float*)d_in[19], (const float*)d_in[20],
        (const float*)d_in[25], (const float*)d_in[26]); }
    { dim3 g(224, 2); k_gemv_fc2<<<g, 256, 0, stream>>>(hbuf, w2T,
        (const float*)d_in[16], (const float*)d_in[22], (const float*)d_in[28],
        (float*)d_out); }
}